// Round 3
// baseline (410.436 us; speedup 1.0000x reference)
//
#include <hip/hip_runtime.h>
#include <stdint.h>

typedef unsigned int u32;
typedef unsigned short u16;

#define GN_EPS 1e-5f

// ---------- bf16 helpers ----------
__device__ __forceinline__ float bflo(u32 u){ return __uint_as_float(u << 16); }
__device__ __forceinline__ float bfhi(u32 u){ return __uint_as_float(u & 0xffff0000u); }
__device__ __forceinline__ u16 f2bf(float f){
  u32 x = __float_as_uint(f);
  u32 r = (x + 0x7fffu + ((x >> 16) & 1u)) >> 16;   // RNE
  return (u16)r;
}
__device__ __forceinline__ u32 pack2(float a, float b){
  return (u32)f2bf(a) | ((u32)f2bf(b) << 16);
}
__device__ __forceinline__ void unpack8(const uint4 u, float* f){
  f[0]=bflo(u.x); f[1]=bfhi(u.x); f[2]=bflo(u.y); f[3]=bfhi(u.y);
  f[4]=bflo(u.z); f[5]=bfhi(u.z); f[6]=bflo(u.w); f[7]=bfhi(u.w);
}

// ---------- dtype-adaptive input load / output store (8 elems, 8-aligned) ----------
__device__ __forceinline__ void load8(const void* base, size_t elem, int f32, float* out){
  if (f32) {
    const float* p = (const float*)base + elem;
    float4 a = *(const float4*)p;
    float4 b = *(const float4*)(p + 4);
    out[0]=a.x; out[1]=a.y; out[2]=a.z; out[3]=a.w;
    out[4]=b.x; out[5]=b.y; out[6]=b.z; out[7]=b.w;
  } else {
    const u16* p = (const u16*)base + elem;
    uint4 v = *(const uint4*)p;
    unpack8(v, out);
  }
}
__device__ __forceinline__ void store8(void* base, size_t elem, int f32, const float* v){
  if (f32) {
    float* p = (float*)base + elem;
    *(float4*)p       = make_float4(v[0],v[1],v[2],v[3]);
    *(float4*)(p + 4) = make_float4(v[4],v[5],v[6],v[7]);
  } else {
    u16* p = (u16*)base + elem;
    *(uint4*)p = make_uint4(pack2(v[0],v[1]),pack2(v[2],v[3]),
                            pack2(v[4],v[5]),pack2(v[6],v[7]));
  }
}

// batch accessor: int32 or int64 (little-endian low word; values < 2^31)
__device__ __forceinline__ int getb(const int* __restrict__ b, int is64, int i){
  return b[is64 ? 2*i : i];
}

// =====================================================================
// K0: detect batch width (flags[0]) and float dtype (flags[1]).
//  - int64 viewed as int32 = [v,0,v,0,..] -> non-monotone once v>0.
//  - f32 N(0,1) words: |f32| in [1e-6,1e3]. bf16-pair words: ~2^±125. 
// =====================================================================
__global__ __launch_bounds__(256) void k_detect(
    const int* __restrict__ batch, const void* __restrict__ x,
    int n, int* __restrict__ flags)
{
  __shared__ int cnt;
  const int t = threadIdx.x;
  if (t == 0) { cnt = 0; flags[0] = 0; }
  __syncthreads();
  int bad = 0;
  for (int i = t; i < n - 1; i += 256)
    if (batch[i] > batch[i + 1]) bad = 1;
  if (bad) atomicOr(&flags[0], 1);
  float f = fabsf(__uint_as_float(((const u32*)x)[t]));
  if (f >= 1e-6f && f <= 1e3f) atomicAdd(&cnt, 1);
  __syncthreads();
  if (t == 0) flags[1] = (cnt > 128) ? 1 : 0;
}

// =====================================================================
// K1: y = x @ w_pre^T + b_pre  (f32 out to ws). 64 nodes x 256 ch / block.
// =====================================================================
__global__ __launch_bounds__(256) void k_pre(
    const void* __restrict__ x, const void* __restrict__ wpre,
    const void* __restrict__ bpre, const int* __restrict__ flags,
    float* __restrict__ y, int N)
{
  __shared__ float xs[32][64];     // [k][m]
  __shared__ float wsf[32][256];   // [k][o]
  const int t  = threadIdx.x;
  const int f32 = flags[1];
  const int n0 = blockIdx.x * 64;
  const int mg = t >> 5, oc = t & 31;
  const int m0 = mg * 8, o0 = oc * 8;

  float acc[8][8];
#pragma unroll
  for (int i = 0; i < 8; i++)
#pragma unroll
    for (int j = 0; j < 8; j++) acc[i][j] = 0.f;

  for (int kc = 0; kc < 256; kc += 32) {
    __syncthreads();
    { // stage x
      int m = t & 63, k8 = (t >> 6) * 8;
      int node = n0 + m;
      float f[8];
      if (node < N) load8(x, (size_t)node*256 + kc + k8, f32, f);
      else { for (int j = 0; j < 8; j++) f[j] = 0.f; }
#pragma unroll
      for (int j = 0; j < 8; j++) xs[k8+j][m] = f[j];
    }
    { // stage w_pre row o=t, k in [kc,kc+32)
#pragma unroll
      for (int c = 0; c < 4; c++) {
        float f[8];
        load8(wpre, (size_t)t*256 + kc + c*8, f32, f);
#pragma unroll
        for (int j = 0; j < 8; j++) wsf[c*8+j][t] = f[j];
      }
    }
    __syncthreads();
#pragma unroll 2
    for (int k = 0; k < 32; k++) {
      const float4 A0 = *(const float4*)&xs[k][m0];
      const float4 A1 = *(const float4*)&xs[k][m0+4];
      const float4 W0 = *(const float4*)&wsf[k][o0];
      const float4 W1 = *(const float4*)&wsf[k][o0+4];
      const float av[8] = {A0.x,A0.y,A0.z,A0.w,A1.x,A1.y,A1.z,A1.w};
      const float bv[8] = {W0.x,W0.y,W0.z,W0.w,W1.x,W1.y,W1.z,W1.w};
#pragma unroll
      for (int mi = 0; mi < 8; mi++)
#pragma unroll
        for (int oi = 0; oi < 8; oi++)
          acc[mi][oi] = fmaf(av[mi], bv[oi], acc[mi][oi]);
    }
  }
  float bpf[8]; load8(bpre, o0, f32, bpf);
#pragma unroll
  for (int mi = 0; mi < 8; mi++) {
    int node = n0 + m0 + mi;
    if (node < N) {
      float4 r0 = make_float4(acc[mi][0]+bpf[0], acc[mi][1]+bpf[1],
                              acc[mi][2]+bpf[2], acc[mi][3]+bpf[3]);
      float4 r1 = make_float4(acc[mi][4]+bpf[4], acc[mi][5]+bpf[5],
                              acc[mi][6]+bpf[6], acc[mi][7]+bpf[7]);
      *(float4*)&y[(size_t)node*256 + o0]     = r0;
      *(float4*)&y[(size_t)node*256 + o0 + 4] = r1;
    }
  }
}

// =====================================================================
// K2: GroupNorm + grouped q/k/v (exp+0.25 scale on q,k only; v plain).
// 32 nodes/block; weights staged per-tensor in f32 LDS (padded stride).
// =====================================================================
__device__ __forceinline__ void load_gn(const float* __restrict__ yrow, float* yn){
  float4 v0 = *(const float4*)(yrow);
  float4 v1 = *(const float4*)(yrow + 4);
  float4 v2 = *(const float4*)(yrow + 8);
  float4 v3 = *(const float4*)(yrow + 12);
  float a[16] = {v0.x,v0.y,v0.z,v0.w, v1.x,v1.y,v1.z,v1.w,
                 v2.x,v2.y,v2.z,v2.w, v3.x,v3.y,v3.z,v3.w};
  float mu = 0.f;
#pragma unroll
  for (int i = 0; i < 16; i++) mu += a[i];
  mu *= 0.0625f;
  float s2 = 0.f;
#pragma unroll
  for (int i = 0; i < 16; i++) { float d = a[i]-mu; s2 = fmaf(d,d,s2); }
  float inv = rsqrtf(s2*0.0625f + GN_EPS);
#pragma unroll
  for (int i = 0; i < 16; i++) yn[i] = (a[i]-mu)*inv;
}

__global__ __launch_bounds__(256) void k_gnqkv(
    const float* __restrict__ y, const void* __restrict__ wq,
    const void* __restrict__ wk, const void* __restrict__ wv,
    const int* __restrict__ flags,
    u16* __restrict__ qo, u16* __restrict__ ko, u16* __restrict__ vo, int N)
{
  __shared__ float wsf[16*520];   // one tensor at a time; 512+8 pad per group
  const int t = threadIdx.x;
  const int f32 = flags[1];
  const int g  = t & 15;
  const int mp = t >> 4;
  const int node0 = blockIdx.x*32 + mp*2;
  const int node1 = node0 + 1;
  const bool val0 = node0 < N, val1 = node1 < N;

  float yn0[16], yn1[16];
  if (val0) load_gn(y + (size_t)node0*256 + g*16, yn0);
  else { for (int i = 0; i < 16; i++) yn0[i] = 0.f; }
  if (val1) load_gn(y + (size_t)node1*256 + g*16, yn1);
  else { for (int i = 0; i < 16; i++) yn1[i] = 0.f; }

  const void* srcs[3] = {wq, wk, wv};
  u16* outs[3] = {qo, ko, vo};

  for (int tz = 0; tz < 3; tz++) {
    __syncthreads();
    for (int c = t; c < 1024; c += 256) {      // 8192 elems in 8-chunks
      float f[8];
      load8(srcs[tz], (size_t)c*8, f32, f);
      float* dst = &wsf[(c >> 6)*520 + (c & 63)*8];
#pragma unroll
      for (int j = 0; j < 8; j++) dst[j] = f[j];
    }
    __syncthreads();
#pragma unroll
    for (int s = 0; s < 2; s++) {
      u32 p0[8], p1[8];
#pragma unroll
      for (int o = 0; o < 16; o++) {
        const float* row = &wsf[g*520 + (s*16 + o)*16];
        float4 W0 = *(const float4*)row;
        float4 W1 = *(const float4*)(row + 4);
        float4 W2 = *(const float4*)(row + 8);
        float4 W3 = *(const float4*)(row + 12);
        float w[16] = {W0.x,W0.y,W0.z,W0.w,W1.x,W1.y,W1.z,W1.w,
                       W2.x,W2.y,W2.z,W2.w,W3.x,W3.y,W3.z,W3.w};
        float a0 = 0.f, a1 = 0.f;
#pragma unroll
        for (int i = 0; i < 16; i++) {
          a0 = fmaf(yn0[i], w[i], a0);
          a1 = fmaf(yn1[i], w[i], a1);
        }
        if (tz < 2) { a0 = __expf(a0*0.25f); a1 = __expf(a1*0.25f); }  // q,k only
        if (o & 1) { p0[o>>1] |= (u32)f2bf(a0) << 16; p1[o>>1] |= (u32)f2bf(a1) << 16; }
        else       { p0[o>>1]  = (u32)f2bf(a0);       p1[o>>1]  = (u32)f2bf(a1); }
      }
      int base0 = node0*512 + (g*2 + s)*16;
      if (val0) {
        *(uint4*)&outs[tz][base0]     = make_uint4(p0[0],p0[1],p0[2],p0[3]);
        *(uint4*)&outs[tz][base0 + 8] = make_uint4(p0[4],p0[5],p0[6],p0[7]);
      }
      if (val1) {
        int base1 = base0 + 512;
        *(uint4*)&outs[tz][base1]     = make_uint4(p1[0],p1[1],p1[2],p1[3]);
        *(uint4*)&outs[tz][base1 + 8] = make_uint4(p1[4],p1[5],p1[6],p1[7]);
      }
    }
  }
}

// =====================================================================
// K3: per-graph segment sums; out1 = kv_sum + x_res (dtype-adaptive out).
// =====================================================================
__device__ __forceinline__ int lbound(const int* __restrict__ a, int is64,
                                      int lo, int n, int key){
  int l = lo, h = n;
  while (l < h) { int m = (l + h) >> 1; if (getb(a, is64, m) < key) l = m + 1; else h = m; }
  return l;
}

__global__ __launch_bounds__(256) void k_seg(
    const u16* __restrict__ xk, const u16* __restrict__ xv,
    const void* __restrict__ xres, const int* __restrict__ batch,
    const int* __restrict__ flags,
    float* __restrict__ ksum, void* __restrict__ dout, size_t out1_off, int N)
{
  __shared__ float ksh[4][512];
  __shared__ float vsh[4][512];
  const int b = blockIdx.x, t = threadIdx.x;
  const int is64 = flags[0], f32 = flags[1];
  const int lo = lbound(batch, is64, 0, N, b);
  const int hi = lbound(batch, is64, lo, N, b + 1);

  float kv[2][16];
#pragma unroll
  for (int r = 0; r < 2; r++)
#pragma unroll
    for (int v = 0; v < 16; v++) kv[r][v] = 0.f;
  float ks0 = 0.f, ks1 = 0.f;
  const int nh = t >> 3, hp = t & 7;

  for (int base = lo; base < hi; base += 4) {
    __syncthreads();
    {
      int j = t >> 6, e8 = (t & 63)*8;
      uint4 K4 = make_uint4(0u,0u,0u,0u), V4 = make_uint4(0u,0u,0u,0u);
      int node = base + j;
      if (node < hi) {
        K4 = *(const uint4*)(xk + (size_t)node*512 + e8);
        V4 = *(const uint4*)(xv + (size_t)node*512 + e8);
      }
      float kf[8], vf[8]; unpack8(K4, kf); unpack8(V4, vf);
#pragma unroll
      for (int i = 0; i < 8; i++) { ksh[j][e8+i] = kf[i]; vsh[j][e8+i] = vf[i]; }
    }
    __syncthreads();
#pragma unroll
    for (int j = 0; j < 4; j++) {
      float k0 = ksh[j][nh*16 + 2*hp], k1 = ksh[j][nh*16 + 2*hp + 1];
      float4 V0 = *(const float4*)&vsh[j][nh*16];
      float4 V1 = *(const float4*)&vsh[j][nh*16 + 4];
      float4 V2 = *(const float4*)&vsh[j][nh*16 + 8];
      float4 V3 = *(const float4*)&vsh[j][nh*16 + 12];
      float vv[16] = {V0.x,V0.y,V0.z,V0.w,V1.x,V1.y,V1.z,V1.w,
                      V2.x,V2.y,V2.z,V2.w,V3.x,V3.y,V3.z,V3.w};
#pragma unroll
      for (int v = 0; v < 16; v++) {
        kv[0][v] = fmaf(k0, vv[v], kv[0][v]);
        kv[1][v] = fmaf(k1, vv[v], kv[1][v]);
      }
      ks0 += ksh[j][2*t]; ks1 += ksh[j][2*t + 1];
    }
  }
  *(float2*)&ksum[(size_t)b*512 + 2*t] = make_float2(ks0, ks1);
#pragma unroll
  for (int r = 0; r < 2; r++) {
    int h = 2*hp + r;
    size_t idx = ((size_t)(b*32 + nh)*16 + h)*16;
    float xf[16];
    load8(xres, idx, f32, xf);
    load8(xres, idx + 8, f32, xf + 8);
    float o[16];
#pragma unroll
    for (int j = 0; j < 16; j++) o[j] = kv[r][j] + xf[j];
    store8(dout, out1_off + idx, f32, o);
    store8(dout, out1_off + idx + 8, f32, o + 8);
  }
}

// =====================================================================
// K4: denom, qn, att = qn . kv_sum[batch]  (kv_sum read from out1)
// =====================================================================
__global__ __launch_bounds__(256) void k_att(
    const u16* __restrict__ xq, const float* __restrict__ ksum,
    const void* __restrict__ dout, size_t out1_off,
    const int* __restrict__ batch, const int* __restrict__ flags,
    u16* __restrict__ att, int N, int B)
{
  const int t = threadIdx.x;
  const int node = blockIdx.x*8 + (t >> 5);
  const int nh = t & 31;
  if (node >= N) return;
  const int is64 = flags[0], f32 = flags[1];
  int b = getb(batch, is64, node);
  b = b < 0 ? 0 : (b >= B ? B - 1 : b);

  uint4 Q0 = *(const uint4*)(xq + (size_t)node*512 + nh*16);
  uint4 Q1 = *(const uint4*)(xq + (size_t)node*512 + nh*16 + 8);
  float q[16]; unpack8(Q0, q); unpack8(Q1, q + 8);

  const float* ksp = ksum + (size_t)b*512 + nh*16;
  float4 S0 = *(const float4*)ksp;
  float4 S1 = *(const float4*)(ksp + 4);
  float4 S2 = *(const float4*)(ksp + 8);
  float4 S3 = *(const float4*)(ksp + 12);
  float ks[16] = {S0.x,S0.y,S0.z,S0.w,S1.x,S1.y,S1.z,S1.w,
                  S2.x,S2.y,S2.z,S2.w,S3.x,S3.y,S3.z,S3.w};
  float denom = 0.f;
#pragma unroll
  for (int i = 0; i < 16; i++) denom = fmaf(q[i], ks[i], denom);
  float inv = 1.0f / fmaxf(denom, 1e-20f);
  float qn[16];
#pragma unroll
  for (int i = 0; i < 16; i++) qn[i] = q[i] * inv;

  float a[16];
#pragma unroll
  for (int v = 0; v < 16; v++) a[v] = 0.f;
  const size_t kvrow = out1_off + (size_t)(b*32 + nh)*256;
#pragma unroll
  for (int h = 0; h < 16; h++) {
    float w[16];
    load8(dout, kvrow + h*16, f32, w);
    load8(dout, kvrow + h*16 + 8, f32, w + 8);
#pragma unroll
    for (int v = 0; v < 16; v++) a[v] = fmaf(qn[h], w[v], a[v]);
  }
  u32 p[8];
#pragma unroll
  for (int j = 0; j < 8; j++) p[j] = pack2(a[2*j], a[2*j+1]);
  u16* dst = att + (size_t)node*512 + nh*16;
  *(uint4*)dst       = make_uint4(p[0],p[1],p[2],p[3]);
  *(uint4*)(dst + 8) = make_uint4(p[4],p[5],p[6],p[7]);
}

// =====================================================================
// K5: out0 = exp(log_scale) * (att @ w_post^T + b_post)  (K=512)
// =====================================================================
__global__ __launch_bounds__(256) void k_post(
    const u16* __restrict__ att, const void* __restrict__ wpost,
    const void* __restrict__ bpost, const void* __restrict__ ls,
    const int* __restrict__ flags, void* __restrict__ dout, int N)
{
  __shared__ float xs[32][64];
  __shared__ __align__(16) u16 wsh[32][256];
  const int t  = threadIdx.x;
  const int f32 = flags[1];
  const int n0 = blockIdx.x * 64;
  const int mg = t >> 5, oc = t & 31;
  const int m0 = mg * 8, o0 = oc * 8;

  float acc[8][8];
#pragma unroll
  for (int i = 0; i < 8; i++)
#pragma unroll
    for (int j = 0; j < 8; j++) acc[i][j] = 0.f;

  for (int kc = 0; kc < 512; kc += 32) {
    __syncthreads();
    { // stage att (bf16 ws)
      int m = t & 63, k8 = (t >> 6) * 8;
      int node = n0 + m;
      uint4 v = make_uint4(0u,0u,0u,0u);
      if (node < N) v = *(const uint4*)(att + (size_t)node*512 + kc + k8);
      float f[8]; unpack8(v, f);
#pragma unroll
      for (int j = 0; j < 8; j++) xs[k8+j][m] = f[j];
    }
    { // stage w_post row o=t (dtype-adaptive), store bf16 in LDS
#pragma unroll
      for (int c = 0; c < 4; c++) {
        float f[8];
        load8(wpost, (size_t)t*512 + kc + c*8, f32, f);
#pragma unroll
        for (int j = 0; j < 8; j++) wsh[c*8+j][t] = f2bf(f[j]);
      }
    }
    __syncthreads();
#pragma unroll 2
    for (int k = 0; k < 32; k++) {
      const float4 A0 = *(const float4*)&xs[k][m0];
      const float4 A1 = *(const float4*)&xs[k][m0+4];
      const uint4  W  = *(const uint4*)&wsh[k][o0];
      float bv[8] = {bflo(W.x),bfhi(W.x),bflo(W.y),bfhi(W.y),
                     bflo(W.z),bfhi(W.z),bflo(W.w),bfhi(W.w)};
      const float av[8] = {A0.x,A0.y,A0.z,A0.w,A1.x,A1.y,A1.z,A1.w};
#pragma unroll
      for (int mi = 0; mi < 8; mi++)
#pragma unroll
        for (int oi = 0; oi < 8; oi++)
          acc[mi][oi] = fmaf(av[mi], bv[oi], acc[mi][oi]);
    }
  }
  float lsf[8], bpf[8];
  load8(ls, o0, f32, lsf);
  load8(bpost, o0, f32, bpf);
  float els[8];
#pragma unroll
  for (int i = 0; i < 8; i++) els[i] = __expf(lsf[i]);
#pragma unroll
  for (int mi = 0; mi < 8; mi++) {
    int node = n0 + m0 + mi;
    if (node < N) {
      float o[8];
#pragma unroll
      for (int j = 0; j < 8; j++) o[j] = els[j]*(acc[mi][j]+bpf[j]);
      store8(dout, (size_t)node*256 + o0, f32, o);
    }
  }
}

// =====================================================================
extern "C" void kernel_launch(void* const* d_in, const int* in_sizes, int n_in,
                              void* d_out, int out_size, void* d_ws, size_t ws_size,
                              hipStream_t stream)
{
  const void* x     = d_in[0];
  const void* xres  = d_in[1];
  const int*  batch = (const int*)d_in[2];
  const void* wpre  = d_in[4];
  const void* bpre  = d_in[5];
  const void* wq    = d_in[6];
  const void* wk    = d_in[7];
  const void* wv    = d_in[8];
  const void* wpost = d_in[9];
  const void* bpost = d_in[10];
  const void* ls    = d_in[11];

  const int N = in_sizes[0] / 256;     // 20000 nodes
  const int B = in_sizes[1] / 8192;    // 1024 graphs

  char* ws = (char*)d_ws;
  size_t off = 0;
  int*   flags = (int*)(ws + off); off += 256;
  float* y     = (float*)(ws + off);                           // reused for att
  u16*   att   = (u16*)(ws + off);  off += (size_t)N * 1024;
  u16*   q     = (u16*)(ws + off);  off += (size_t)N * 1024;
  u16*   kten  = (u16*)(ws + off);  off += (size_t)N * 1024;
  u16*   vten  = (u16*)(ws + off);  off += (size_t)N * 1024;
  float* ksum  = (float*)(ws + off); off += (size_t)B * 2048;

  const size_t out1_off = (size_t)N * 256;   // elements

  k_detect<<<1,             256, 0, stream>>>(batch, x, N, flags);
  k_pre  <<<(N + 63) / 64,  256, 0, stream>>>(x, wpre, bpre, flags, y, N);
  k_gnqkv<<<(N + 31) / 32,  256, 0, stream>>>(y, wq, wk, wv, flags, q, kten, vten, N);
  k_seg  <<<B,              256, 0, stream>>>(kten, vten, xres, batch, flags, ksum,
                                              d_out, out1_off, N);
  k_att  <<<(N + 7) / 8,    256, 0, stream>>>(q, ksum, d_out, out1_off, batch, flags,
                                              att, N, B);
  k_post <<<(N + 63) / 64,  256, 0, stream>>>(att, wpost, bpost, ls, flags, d_out, N);
}

// Round 4
// 275.635 us; speedup vs baseline: 1.4891x; 1.4891x over previous
//
#include <hip/hip_runtime.h>
#include <stdint.h>

typedef unsigned int u32;
typedef unsigned short u16;
typedef __attribute__((ext_vector_type(8))) short v8s;   // 8 bf16 (4 VGPRs)
typedef __attribute__((ext_vector_type(4))) float v4f;   // 4 f32 acc

#define GN_EPS 1e-5f

// ---------- bf16 helpers ----------
__device__ __forceinline__ float bflo(u32 u){ return __uint_as_float(u << 16); }
__device__ __forceinline__ float bfhi(u32 u){ return __uint_as_float(u & 0xffff0000u); }
__device__ __forceinline__ u16 f2bf(float f){
  u32 x = __float_as_uint(f);
  u32 r = (x + 0x7fffu + ((x >> 16) & 1u)) >> 16;   // RNE
  return (u16)r;
}
__device__ __forceinline__ u32 pack2(float a, float b){
  return (u32)f2bf(a) | ((u32)f2bf(b) << 16);
}
__device__ __forceinline__ void unpack8(const uint4 u, float* f){
  f[0]=bflo(u.x); f[1]=bfhi(u.x); f[2]=bflo(u.y); f[3]=bfhi(u.y);
  f[4]=bflo(u.z); f[5]=bfhi(u.z); f[6]=bflo(u.w); f[7]=bfhi(u.w);
}

// ---------- dtype-adaptive helpers ----------
__device__ __forceinline__ void load8(const void* base, size_t elem, int f32, float* out){
  if (f32) {
    const float* p = (const float*)base + elem;
    float4 a = *(const float4*)p;
    float4 b = *(const float4*)(p + 4);
    out[0]=a.x; out[1]=a.y; out[2]=a.z; out[3]=a.w;
    out[4]=b.x; out[5]=b.y; out[6]=b.z; out[7]=b.w;
  } else {
    const u16* p = (const u16*)base + elem;
    uint4 v = *(const uint4*)p;
    unpack8(v, out);
  }
}
__device__ __forceinline__ void store8(void* base, size_t elem, int f32, const float* v){
  if (f32) {
    float* p = (float*)base + elem;
    *(float4*)p       = make_float4(v[0],v[1],v[2],v[3]);
    *(float4*)(p + 4) = make_float4(v[4],v[5],v[6],v[7]);
  } else {
    u16* p = (u16*)base + elem;
    *(uint4*)p = make_uint4(pack2(v[0],v[1]),pack2(v[2],v[3]),
                            pack2(v[4],v[5]),pack2(v[6],v[7]));
  }
}
__device__ __forceinline__ float loadS(const void* base, size_t i, int f32){
  return f32 ? ((const float*)base)[i]
             : __uint_as_float((u32)((const u16*)base)[i] << 16);
}
__device__ __forceinline__ void storeS(void* base, size_t i, int f32, float v){
  if (f32) ((float*)base)[i] = v; else ((u16*)base)[i] = f2bf(v);
}
// load 8 elems from adaptive source, return packed bf16 (4 u32)
__device__ __forceinline__ uint4 load8bf(const void* base, size_t elem, int f32){
  if (f32) {
    float f[8]; load8(base, elem, 1, f);
    return make_uint4(pack2(f[0],f[1]),pack2(f[2],f[3]),pack2(f[4],f[5]),pack2(f[6],f[7]));
  }
  return *(const uint4*)((const u16*)base + elem);
}

// batch accessor: int32 or int64 (little-endian low word)
__device__ __forceinline__ int getb(const int* __restrict__ b, int is64, int i){
  return b[is64 ? 2*i : i];
}

// =====================================================================
// K0: detect batch width (flags[0]) and float dtype (flags[1]).
// =====================================================================
__global__ __launch_bounds__(256) void k_detect(
    const int* __restrict__ batch, const void* __restrict__ x,
    int n, int* __restrict__ flags)
{
  __shared__ int cnt;
  const int t = threadIdx.x;
  if (t == 0) { cnt = 0; flags[0] = 0; }
  __syncthreads();
  int bad = 0;
  for (int i = t; i < n - 1; i += 256)
    if (batch[i] > batch[i + 1]) bad = 1;
  if (bad) atomicOr(&flags[0], 1);
  float f = fabsf(__uint_as_float(((const u32*)x)[t]));
  if (f >= 1e-6f && f <= 1e3f) atomicAdd(&cnt, 1);
  __syncthreads();
  if (t == 0) flags[1] = (cnt > 128) ? 1 : 0;
}

// =====================================================================
// K1 (MFMA): y = x @ w_pre^T + b_pre, f32 out. Tile 64x64, 4 waves 2x2,
// mfma_f32_16x16x32_bf16, K=256. LDS rows padded to 40 elems (80 B).
// =====================================================================
__global__ __launch_bounds__(256) void k_pre(
    const void* __restrict__ x, const void* __restrict__ wpre,
    const void* __restrict__ bpre, const int* __restrict__ flags,
    float* __restrict__ y, int N, int nbm)
{
  __shared__ __align__(16) u16 As[64*40];
  __shared__ __align__(16) u16 Bs[64*40];
  const int t = threadIdx.x;
  const int f32 = flags[1];
  const int bm = blockIdx.x % nbm;
  const int bn = blockIdx.x / nbm;          // 0..3
  const int m_base = bm*64, n_base = bn*64;
  const int w = t >> 6, lane = t & 63;
  const int wm = (w >> 1)*32, wn = (w & 1)*32;
  const int fr = lane & 15, fk = lane >> 4;
  const int srow = t >> 2, scol = (t & 3)*8;

  v4f acc[2][2];
#pragma unroll
  for (int i = 0; i < 2; i++)
#pragma unroll
    for (int j = 0; j < 2; j++) acc[i][j] = (v4f){0.f,0.f,0.f,0.f};

  for (int k0 = 0; k0 < 256; k0 += 32) {
    __syncthreads();
    {
      int gm = m_base + srow;
      uint4 av = make_uint4(0u,0u,0u,0u);
      if (gm < N) av = load8bf(x, (size_t)gm*256 + k0 + scol, f32);
      *(uint4*)&As[srow*40 + scol] = av;
      uint4 bv = load8bf(wpre, (size_t)(n_base + srow)*256 + k0 + scol, f32);
      *(uint4*)&Bs[srow*40 + scol] = bv;
    }
    __syncthreads();
    v8s a0 = *(const v8s*)&As[(wm      + fr)*40 + fk*8];
    v8s a1 = *(const v8s*)&As[(wm + 16 + fr)*40 + fk*8];
    v8s b0 = *(const v8s*)&Bs[(wn      + fr)*40 + fk*8];
    v8s b1 = *(const v8s*)&Bs[(wn + 16 + fr)*40 + fk*8];
    acc[0][0] = __builtin_amdgcn_mfma_f32_16x16x32_bf16(a0,b0,acc[0][0],0,0,0);
    acc[0][1] = __builtin_amdgcn_mfma_f32_16x16x32_bf16(a0,b1,acc[0][1],0,0,0);
    acc[1][0] = __builtin_amdgcn_mfma_f32_16x16x32_bf16(a1,b0,acc[1][0],0,0,0);
    acc[1][1] = __builtin_amdgcn_mfma_f32_16x16x32_bf16(a1,b1,acc[1][1],0,0,0);
  }
#pragma unroll
  for (int nj = 0; nj < 2; nj++) {
    int col = n_base + wn + nj*16 + fr;
    float bpv = loadS(bpre, col, f32);
#pragma unroll
    for (int mi = 0; mi < 2; mi++) {
#pragma unroll
      for (int r = 0; r < 4; r++) {
        int row = m_base + wm + mi*16 + fk*4 + r;
        if (row < N) y[(size_t)row*256 + col] = acc[mi][nj][r] + bpv;
      }
    }
  }
}

// =====================================================================
// K2: GroupNorm + grouped q/k/v (exp+0.25 on q,k; v plain). unchanged.
// =====================================================================
__device__ __forceinline__ void load_gn(const float* __restrict__ yrow, float* yn){
  float4 v0 = *(const float4*)(yrow);
  float4 v1 = *(const float4*)(yrow + 4);
  float4 v2 = *(const float4*)(yrow + 8);
  float4 v3 = *(const float4*)(yrow + 12);
  float a[16] = {v0.x,v0.y,v0.z,v0.w, v1.x,v1.y,v1.z,v1.w,
                 v2.x,v2.y,v2.z,v2.w, v3.x,v3.y,v3.z,v3.w};
  float mu = 0.f;
#pragma unroll
  for (int i = 0; i < 16; i++) mu += a[i];
  mu *= 0.0625f;
  float s2 = 0.f;
#pragma unroll
  for (int i = 0; i < 16; i++) { float d = a[i]-mu; s2 = fmaf(d,d,s2); }
  float inv = rsqrtf(s2*0.0625f + GN_EPS);
#pragma unroll
  for (int i = 0; i < 16; i++) yn[i] = (a[i]-mu)*inv;
}

__global__ __launch_bounds__(256) void k_gnqkv(
    const float* __restrict__ y, const void* __restrict__ wq,
    const void* __restrict__ wk, const void* __restrict__ wv,
    const int* __restrict__ flags,
    u16* __restrict__ qo, u16* __restrict__ ko, u16* __restrict__ vo, int N)
{
  __shared__ float wsf[16*520];
  const int t = threadIdx.x;
  const int f32 = flags[1];
  const int g  = t & 15;
  const int mp = t >> 4;
  const int node0 = blockIdx.x*32 + mp*2;
  const int node1 = node0 + 1;
  const bool val0 = node0 < N, val1 = node1 < N;

  float yn0[16], yn1[16];
  if (val0) load_gn(y + (size_t)node0*256 + g*16, yn0);
  else { for (int i = 0; i < 16; i++) yn0[i] = 0.f; }
  if (val1) load_gn(y + (size_t)node1*256 + g*16, yn1);
  else { for (int i = 0; i < 16; i++) yn1[i] = 0.f; }

  const void* srcs[3] = {wq, wk, wv};
  u16* outs[3] = {qo, ko, vo};

  for (int tz = 0; tz < 3; tz++) {
    __syncthreads();
    for (int c = t; c < 1024; c += 256) {
      float f[8];
      load8(srcs[tz], (size_t)c*8, f32, f);
      float* dst = &wsf[(c >> 6)*520 + (c & 63)*8];
#pragma unroll
      for (int j = 0; j < 8; j++) dst[j] = f[j];
    }
    __syncthreads();
#pragma unroll
    for (int s = 0; s < 2; s++) {
      u32 p0[8], p1[8];
#pragma unroll
      for (int o = 0; o < 16; o++) {
        const float* row = &wsf[g*520 + (s*16 + o)*16];
        float4 W0 = *(const float4*)row;
        float4 W1 = *(const float4*)(row + 4);
        float4 W2 = *(const float4*)(row + 8);
        float4 W3 = *(const float4*)(row + 12);
        float w[16] = {W0.x,W0.y,W0.z,W0.w,W1.x,W1.y,W1.z,W1.w,
                       W2.x,W2.y,W2.z,W2.w,W3.x,W3.y,W3.z,W3.w};
        float a0 = 0.f, a1 = 0.f;
#pragma unroll
        for (int i = 0; i < 16; i++) {
          a0 = fmaf(yn0[i], w[i], a0);
          a1 = fmaf(yn1[i], w[i], a1);
        }
        if (tz < 2) { a0 = __expf(a0*0.25f); a1 = __expf(a1*0.25f); }
        if (o & 1) { p0[o>>1] |= (u32)f2bf(a0) << 16; p1[o>>1] |= (u32)f2bf(a1) << 16; }
        else       { p0[o>>1]  = (u32)f2bf(a0);       p1[o>>1]  = (u32)f2bf(a1); }
      }
      int base0 = node0*512 + (g*2 + s)*16;
      if (val0) {
        *(uint4*)&outs[tz][base0]     = make_uint4(p0[0],p0[1],p0[2],p0[3]);
        *(uint4*)&outs[tz][base0 + 8] = make_uint4(p0[4],p0[5],p0[6],p0[7]);
      }
      if (val1) {
        int base1 = base0 + 512;
        *(uint4*)&outs[tz][base1]     = make_uint4(p1[0],p1[1],p1[2],p1[3]);
        *(uint4*)&outs[tz][base1 + 8] = make_uint4(p1[4],p1[5],p1[6],p1[7]);
      }
    }
  }
}

// =====================================================================
// K3: per-graph segment sums; out1 = kv_sum + x_res. unchanged.
// =====================================================================
__device__ __forceinline__ int lbound(const int* __restrict__ a, int is64,
                                      int lo, int n, int key){
  int l = lo, h = n;
  while (l < h) { int m = (l + h) >> 1; if (getb(a, is64, m) < key) l = m + 1; else h = m; }
  return l;
}

__global__ __launch_bounds__(256) void k_seg(
    const u16* __restrict__ xk, const u16* __restrict__ xv,
    const void* __restrict__ xres, const int* __restrict__ batch,
    const int* __restrict__ flags,
    float* __restrict__ ksum, void* __restrict__ dout, size_t out1_off, int N)
{
  __shared__ float ksh[4][512];
  __shared__ float vsh[4][512];
  const int b = blockIdx.x, t = threadIdx.x;
  const int is64 = flags[0], f32 = flags[1];
  const int lo = lbound(batch, is64, 0, N, b);
  const int hi = lbound(batch, is64, lo, N, b + 1);

  float kv[2][16];
#pragma unroll
  for (int r = 0; r < 2; r++)
#pragma unroll
    for (int v = 0; v < 16; v++) kv[r][v] = 0.f;
  float ks0 = 0.f, ks1 = 0.f;
  const int nh = t >> 3, hp = t & 7;

  for (int base = lo; base < hi; base += 4) {
    __syncthreads();
    {
      int j = t >> 6, e8 = (t & 63)*8;
      uint4 K4 = make_uint4(0u,0u,0u,0u), V4 = make_uint4(0u,0u,0u,0u);
      int node = base + j;
      if (node < hi) {
        K4 = *(const uint4*)(xk + (size_t)node*512 + e8);
        V4 = *(const uint4*)(xv + (size_t)node*512 + e8);
      }
      float kf[8], vf[8]; unpack8(K4, kf); unpack8(V4, vf);
#pragma unroll
      for (int i = 0; i < 8; i++) { ksh[j][e8+i] = kf[i]; vsh[j][e8+i] = vf[i]; }
    }
    __syncthreads();
#pragma unroll
    for (int j = 0; j < 4; j++) {
      float k0 = ksh[j][nh*16 + 2*hp], k1 = ksh[j][nh*16 + 2*hp + 1];
      float4 V0 = *(const float4*)&vsh[j][nh*16];
      float4 V1 = *(const float4*)&vsh[j][nh*16 + 4];
      float4 V2 = *(const float4*)&vsh[j][nh*16 + 8];
      float4 V3 = *(const float4*)&vsh[j][nh*16 + 12];
      float vv[16] = {V0.x,V0.y,V0.z,V0.w,V1.x,V1.y,V1.z,V1.w,
                      V2.x,V2.y,V2.z,V2.w,V3.x,V3.y,V3.z,V3.w};
#pragma unroll
      for (int v = 0; v < 16; v++) {
        kv[0][v] = fmaf(k0, vv[v], kv[0][v]);
        kv[1][v] = fmaf(k1, vv[v], kv[1][v]);
      }
      ks0 += ksh[j][2*t]; ks1 += ksh[j][2*t + 1];
    }
  }
  *(float2*)&ksum[(size_t)b*512 + 2*t] = make_float2(ks0, ks1);
#pragma unroll
  for (int r = 0; r < 2; r++) {
    int h = 2*hp + r;
    size_t idx = ((size_t)(b*32 + nh)*16 + h)*16;
    float xf[16];
    load8(xres, idx, f32, xf);
    load8(xres, idx + 8, f32, xf + 8);
    float o[16];
#pragma unroll
    for (int j = 0; j < 16; j++) o[j] = kv[r][j] + xf[j];
    store8(dout, out1_off + idx, f32, o);
    store8(dout, out1_off + idx + 8, f32, o + 8);
  }
}

// =====================================================================
// K4: denom, qn, att = qn . kv_sum[batch]. unchanged.
// =====================================================================
__global__ __launch_bounds__(256) void k_att(
    const u16* __restrict__ xq, const float* __restrict__ ksum,
    const void* __restrict__ dout, size_t out1_off,
    const int* __restrict__ batch, const int* __restrict__ flags,
    u16* __restrict__ att, int N, int B)
{
  const int t = threadIdx.x;
  const int node = blockIdx.x*8 + (t >> 5);
  const int nh = t & 31;
  if (node >= N) return;
  const int is64 = flags[0], f32 = flags[1];
  int b = getb(batch, is64, node);
  b = b < 0 ? 0 : (b >= B ? B - 1 : b);

  uint4 Q0 = *(const uint4*)(xq + (size_t)node*512 + nh*16);
  uint4 Q1 = *(const uint4*)(xq + (size_t)node*512 + nh*16 + 8);
  float q[16]; unpack8(Q0, q); unpack8(Q1, q + 8);

  const float* ksp = ksum + (size_t)b*512 + nh*16;
  float4 S0 = *(const float4*)ksp;
  float4 S1 = *(const float4*)(ksp + 4);
  float4 S2 = *(const float4*)(ksp + 8);
  float4 S3 = *(const float4*)(ksp + 12);
  float ks[16] = {S0.x,S0.y,S0.z,S0.w,S1.x,S1.y,S1.z,S1.w,
                  S2.x,S2.y,S2.z,S2.w,S3.x,S3.y,S3.z,S3.w};
  float denom = 0.f;
#pragma unroll
  for (int i = 0; i < 16; i++) denom = fmaf(q[i], ks[i], denom);
  float inv = 1.0f / fmaxf(denom, 1e-20f);
  float qn[16];
#pragma unroll
  for (int i = 0; i < 16; i++) qn[i] = q[i] * inv;

  float a[16];
#pragma unroll
  for (int v = 0; v < 16; v++) a[v] = 0.f;
  const size_t kvrow = out1_off + (size_t)(b*32 + nh)*256;
#pragma unroll
  for (int h = 0; h < 16; h++) {
    float w[16];
    load8(dout, kvrow + h*16, f32, w);
    load8(dout, kvrow + h*16 + 8, f32, w + 8);
#pragma unroll
    for (int v = 0; v < 16; v++) a[v] = fmaf(qn[h], w[v], a[v]);
  }
  u32 p[8];
#pragma unroll
  for (int j = 0; j < 8; j++) p[j] = pack2(a[2*j], a[2*j+1]);
  u16* dst = att + (size_t)node*512 + nh*16;
  *(uint4*)dst       = make_uint4(p[0],p[1],p[2],p[3]);
  *(uint4*)(dst + 8) = make_uint4(p[4],p[5],p[6],p[7]);
}

// =====================================================================
// K5 (MFMA): out0 = exp(log_scale) * (att @ w_post^T + b_post), K=512.
// att is bf16 ws; w_post adaptive->bf16 staging. Same tile as k_pre.
// =====================================================================
__global__ __launch_bounds__(256) void k_post(
    const u16* __restrict__ att, const void* __restrict__ wpost,
    const void* __restrict__ bpost, const void* __restrict__ ls,
    const int* __restrict__ flags, void* __restrict__ dout, int N, int nbm)
{
  __shared__ __align__(16) u16 As[64*40];
  __shared__ __align__(16) u16 Bs[64*40];
  const int t = threadIdx.x;
  const int f32 = flags[1];
  const int bm = blockIdx.x % nbm;
  const int bn = blockIdx.x / nbm;          // 0..3
  const int m_base = bm*64, n_base = bn*64;
  const int w = t >> 6, lane = t & 63;
  const int wm = (w >> 1)*32, wn = (w & 1)*32;
  const int fr = lane & 15, fk = lane >> 4;
  const int srow = t >> 2, scol = (t & 3)*8;

  v4f acc[2][2];
#pragma unroll
  for (int i = 0; i < 2; i++)
#pragma unroll
    for (int j = 0; j < 2; j++) acc[i][j] = (v4f){0.f,0.f,0.f,0.f};

  for (int k0 = 0; k0 < 512; k0 += 32) {
    __syncthreads();
    {
      int gm = m_base + srow;
      uint4 av = make_uint4(0u,0u,0u,0u);
      if (gm < N) av = *(const uint4*)(att + (size_t)gm*512 + k0 + scol);
      *(uint4*)&As[srow*40 + scol] = av;
      uint4 bv = load8bf(wpost, (size_t)(n_base + srow)*512 + k0 + scol, f32);
      *(uint4*)&Bs[srow*40 + scol] = bv;
    }
    __syncthreads();
    v8s a0 = *(const v8s*)&As[(wm      + fr)*40 + fk*8];
    v8s a1 = *(const v8s*)&As[(wm + 16 + fr)*40 + fk*8];
    v8s b0 = *(const v8s*)&Bs[(wn      + fr)*40 + fk*8];
    v8s b1 = *(const v8s*)&Bs[(wn + 16 + fr)*40 + fk*8];
    acc[0][0] = __builtin_amdgcn_mfma_f32_16x16x32_bf16(a0,b0,acc[0][0],0,0,0);
    acc[0][1] = __builtin_amdgcn_mfma_f32_16x16x32_bf16(a0,b1,acc[0][1],0,0,0);
    acc[1][0] = __builtin_amdgcn_mfma_f32_16x16x32_bf16(a1,b0,acc[1][0],0,0,0);
    acc[1][1] = __builtin_amdgcn_mfma_f32_16x16x32_bf16(a1,b1,acc[1][1],0,0,0);
  }
#pragma unroll
  for (int nj = 0; nj < 2; nj++) {
    int col = n_base + wn + nj*16 + fr;
    float bpv = loadS(bpost, col, f32);
    float e   = __expf(loadS(ls, col, f32));
#pragma unroll
    for (int mi = 0; mi < 2; mi++) {
#pragma unroll
      for (int r = 0; r < 4; r++) {
        int row = m_base + wm + mi*16 + fk*4 + r;
        if (row < N) storeS(dout, (size_t)row*256 + col, f32, e*(acc[mi][nj][r] + bpv));
      }
    }
  }
}

// =====================================================================
extern "C" void kernel_launch(void* const* d_in, const int* in_sizes, int n_in,
                              void* d_out, int out_size, void* d_ws, size_t ws_size,
                              hipStream_t stream)
{
  const void* x     = d_in[0];
  const void* xres  = d_in[1];
  const int*  batch = (const int*)d_in[2];
  const void* wpre  = d_in[4];
  const void* bpre  = d_in[5];
  const void* wq    = d_in[6];
  const void* wk    = d_in[7];
  const void* wv    = d_in[8];
  const void* wpost = d_in[9];
  const void* bpost = d_in[10];
  const void* ls    = d_in[11];

  const int N = in_sizes[0] / 256;     // 20000 nodes
  const int B = in_sizes[1] / 8192;    // 1024 graphs
  const int nbm = (N + 63) / 64;       // 313 row tiles

  char* ws = (char*)d_ws;
  size_t off = 0;
  int*   flags = (int*)(ws + off); off += 256;
  float* y     = (float*)(ws + off);                           // reused for att
  u16*   att   = (u16*)(ws + off);  off += (size_t)N * 1024;
  u16*   q     = (u16*)(ws + off);  off += (size_t)N * 1024;
  u16*   kten  = (u16*)(ws + off);  off += (size_t)N * 1024;
  u16*   vten  = (u16*)(ws + off);  off += (size_t)N * 1024;
  float* ksum  = (float*)(ws + off); off += (size_t)B * 2048;

  const size_t out1_off = (size_t)N * 256;   // elements

  k_detect<<<1,             256, 0, stream>>>(batch, x, N, flags);
  k_pre  <<<nbm * 4,        256, 0, stream>>>(x, wpre, bpre, flags, y, N, nbm);
  k_gnqkv<<<(N + 31) / 32,  256, 0, stream>>>(y, wq, wk, wv, flags, q, kten, vten, N);
  k_seg  <<<B,              256, 0, stream>>>(kten, vten, xres, batch, flags, ksum,
                                              d_out, out1_off, N);
  k_att  <<<(N + 7) / 8,    256, 0, stream>>>(q, ksum, d_out, out1_off, batch, flags,
                                              att, N, B);
  k_post <<<nbm * 4,        256, 0, stream>>>(att, wpost, bpost, ls, flags, d_out, N, nbm);
}

// Round 5
// 186.862 us; speedup vs baseline: 2.1965x; 1.4751x over previous
//
#include <hip/hip_runtime.h>
#include <stdint.h>

typedef unsigned int u32;
typedef unsigned short u16;
typedef __attribute__((ext_vector_type(8))) short v8s;   // 8 bf16 (4 VGPRs)
typedef __attribute__((ext_vector_type(4))) float v4f;   // 4 f32 acc

#define GN_EPS 1e-5f

// ---------- bf16 helpers (intermediates in ws are bf16) ----------
__device__ __forceinline__ float bflo(u32 u){ return __uint_as_float(u << 16); }
__device__ __forceinline__ float bfhi(u32 u){ return __uint_as_float(u & 0xffff0000u); }
__device__ __forceinline__ u16 f2bf(float f){
  u32 x = __float_as_uint(f);
  u32 r = (x + 0x7fffu + ((x >> 16) & 1u)) >> 16;   // RNE
  return (u16)r;
}
__device__ __forceinline__ u32 pack2(float a, float b){
  return (u32)f2bf(a) | ((u32)f2bf(b) << 16);
}
__device__ __forceinline__ void unpack8(const uint4 u, float* f){
  f[0]=bflo(u.x); f[1]=bfhi(u.x); f[2]=bflo(u.y); f[3]=bfhi(u.y);
  f[4]=bflo(u.z); f[5]=bfhi(u.z); f[6]=bflo(u.w); f[7]=bfhi(u.w);
}
// load 8 f32, return packed bf16 (4 u32)
__device__ __forceinline__ uint4 loadpack8(const float* __restrict__ p){
  float4 a = *(const float4*)p, b = *(const float4*)(p + 4);
  return make_uint4(pack2(a.x,a.y),pack2(a.z,a.w),pack2(b.x,b.y),pack2(b.z,b.w));
}

// batch accessor: int32 or int64 (little-endian low word)
__device__ __forceinline__ int getb(const int* __restrict__ b, int is64, int i){
  return b[is64 ? 2*i : i];
}

// =====================================================================
// K0: detect batch int-width. int64 viewed as int32 = [v,0,v,0,..] ->
// non-monotone once any v>0; genuine sorted int32 stays monotone.
// =====================================================================
__global__ __launch_bounds__(256) void k_detect(
    const int* __restrict__ batch, int n, int* __restrict__ flags)
{
  if (threadIdx.x == 0) flags[0] = 0;
  __syncthreads();
  int bad = 0;
  for (int i = threadIdx.x; i < n - 1; i += 256)
    if (batch[i] > batch[i + 1]) bad = 1;
  if (bad) atomicOr(&flags[0], 1);
}

// =====================================================================
// K1 (MFMA): y = x @ w_pre^T + b_pre, f32 out. 64x64 tile, 4 waves 2x2.
// =====================================================================
__global__ __launch_bounds__(256) void k_pre(
    const float* __restrict__ x, const float* __restrict__ wpre,
    const float* __restrict__ bpre, float* __restrict__ y, int N, int nbm)
{
  __shared__ __align__(16) u16 As[64*40];
  __shared__ __align__(16) u16 Bs[64*40];
  const int t = threadIdx.x;
  const int bm = blockIdx.x % nbm;
  const int bn = blockIdx.x / nbm;          // 0..3
  const int m_base = bm*64, n_base = bn*64;
  const int w = t >> 6, lane = t & 63;
  const int wm = (w >> 1)*32, wn = (w & 1)*32;
  const int fr = lane & 15, fk = lane >> 4;
  const int srow = t >> 2, scol = (t & 3)*8;

  v4f acc[2][2];
#pragma unroll
  for (int i = 0; i < 2; i++)
#pragma unroll
    for (int j = 0; j < 2; j++) acc[i][j] = (v4f){0.f,0.f,0.f,0.f};

  for (int k0 = 0; k0 < 256; k0 += 32) {
    __syncthreads();
    {
      int gm = m_base + srow;
      uint4 av = make_uint4(0u,0u,0u,0u);
      if (gm < N) av = loadpack8(x + (size_t)gm*256 + k0 + scol);
      *(uint4*)&As[srow*40 + scol] = av;
      uint4 bv = loadpack8(wpre + (size_t)(n_base + srow)*256 + k0 + scol);
      *(uint4*)&Bs[srow*40 + scol] = bv;
    }
    __syncthreads();
    v8s a0 = *(const v8s*)&As[(wm      + fr)*40 + fk*8];
    v8s a1 = *(const v8s*)&As[(wm + 16 + fr)*40 + fk*8];
    v8s b0 = *(const v8s*)&Bs[(wn      + fr)*40 + fk*8];
    v8s b1 = *(const v8s*)&Bs[(wn + 16 + fr)*40 + fk*8];
    acc[0][0] = __builtin_amdgcn_mfma_f32_16x16x32_bf16(a0,b0,acc[0][0],0,0,0);
    acc[0][1] = __builtin_amdgcn_mfma_f32_16x16x32_bf16(a0,b1,acc[0][1],0,0,0);
    acc[1][0] = __builtin_amdgcn_mfma_f32_16x16x32_bf16(a1,b0,acc[1][0],0,0,0);
    acc[1][1] = __builtin_amdgcn_mfma_f32_16x16x32_bf16(a1,b1,acc[1][1],0,0,0);
  }
#pragma unroll
  for (int nj = 0; nj < 2; nj++) {
    int col = n_base + wn + nj*16 + fr;
    float bpv = bpre[col];
#pragma unroll
    for (int mi = 0; mi < 2; mi++) {
#pragma unroll
      for (int r = 0; r < 4; r++) {
        int row = m_base + wm + mi*16 + fk*4 + r;
        if (row < N) y[(size_t)row*256 + col] = acc[mi][nj][r] + bpv;
      }
    }
  }
}

// =====================================================================
// K2: GroupNorm + grouped q/k/v (exp+0.25 on q,k; v plain). bf16 ws out.
// =====================================================================
__device__ __forceinline__ void load_gn(const float* __restrict__ yrow, float* yn){
  float4 v0 = *(const float4*)(yrow);
  float4 v1 = *(const float4*)(yrow + 4);
  float4 v2 = *(const float4*)(yrow + 8);
  float4 v3 = *(const float4*)(yrow + 12);
  float a[16] = {v0.x,v0.y,v0.z,v0.w, v1.x,v1.y,v1.z,v1.w,
                 v2.x,v2.y,v2.z,v2.w, v3.x,v3.y,v3.z,v3.w};
  float mu = 0.f;
#pragma unroll
  for (int i = 0; i < 16; i++) mu += a[i];
  mu *= 0.0625f;
  float s2 = 0.f;
#pragma unroll
  for (int i = 0; i < 16; i++) { float d = a[i]-mu; s2 = fmaf(d,d,s2); }
  float inv = rsqrtf(s2*0.0625f + GN_EPS);
#pragma unroll
  for (int i = 0; i < 16; i++) yn[i] = (a[i]-mu)*inv;
}

__global__ __launch_bounds__(256) void k_gnqkv(
    const float* __restrict__ y, const float* __restrict__ wq,
    const float* __restrict__ wk, const float* __restrict__ wv,
    u16* __restrict__ qo, u16* __restrict__ ko, u16* __restrict__ vo, int N)
{
  __shared__ float wsf[16*520];
  const int t = threadIdx.x;
  const int g  = t & 15;
  const int mp = t >> 4;
  const int node0 = blockIdx.x*32 + mp*2;
  const int node1 = node0 + 1;
  const bool val0 = node0 < N, val1 = node1 < N;

  float yn0[16], yn1[16];
  if (val0) load_gn(y + (size_t)node0*256 + g*16, yn0);
  else { for (int i = 0; i < 16; i++) yn0[i] = 0.f; }
  if (val1) load_gn(y + (size_t)node1*256 + g*16, yn1);
  else { for (int i = 0; i < 16; i++) yn1[i] = 0.f; }

  const float* srcs[3] = {wq, wk, wv};
  u16* outs[3] = {qo, ko, vo};

  for (int tz = 0; tz < 3; tz++) {
    __syncthreads();
    for (int c = t; c < 1024; c += 256) {
      const float* s = srcs[tz] + (size_t)c*8;
      float4 A = *(const float4*)s;
      float4 Bv = *(const float4*)(s + 4);
      float* dst = &wsf[(c >> 6)*520 + (c & 63)*8];
      dst[0]=A.x; dst[1]=A.y; dst[2]=A.z; dst[3]=A.w;
      dst[4]=Bv.x; dst[5]=Bv.y; dst[6]=Bv.z; dst[7]=Bv.w;
    }
    __syncthreads();
#pragma unroll
    for (int s = 0; s < 2; s++) {
      u32 p0[8], p1[8];
#pragma unroll
      for (int o = 0; o < 16; o++) {
        const float* row = &wsf[g*520 + (s*16 + o)*16];
        float4 W0 = *(const float4*)row;
        float4 W1 = *(const float4*)(row + 4);
        float4 W2 = *(const float4*)(row + 8);
        float4 W3 = *(const float4*)(row + 12);
        float w[16] = {W0.x,W0.y,W0.z,W0.w,W1.x,W1.y,W1.z,W1.w,
                       W2.x,W2.y,W2.z,W2.w,W3.x,W3.y,W3.z,W3.w};
        float a0 = 0.f, a1 = 0.f;
#pragma unroll
        for (int i = 0; i < 16; i++) {
          a0 = fmaf(yn0[i], w[i], a0);
          a1 = fmaf(yn1[i], w[i], a1);
        }
        if (tz < 2) { a0 = __expf(a0*0.25f); a1 = __expf(a1*0.25f); }
        if (o & 1) { p0[o>>1] |= (u32)f2bf(a0) << 16; p1[o>>1] |= (u32)f2bf(a1) << 16; }
        else       { p0[o>>1]  = (u32)f2bf(a0);       p1[o>>1]  = (u32)f2bf(a1); }
      }
      int base0 = node0*512 + (g*2 + s)*16;
      if (val0) {
        *(uint4*)&outs[tz][base0]     = make_uint4(p0[0],p0[1],p0[2],p0[3]);
        *(uint4*)&outs[tz][base0 + 8] = make_uint4(p0[4],p0[5],p0[6],p0[7]);
      }
      if (val1) {
        int base1 = base0 + 512;
        *(uint4*)&outs[tz][base1]     = make_uint4(p1[0],p1[1],p1[2],p1[3]);
        *(uint4*)&outs[tz][base1 + 8] = make_uint4(p1[4],p1[5],p1[6],p1[7]);
      }
    }
  }
}

// =====================================================================
// K3 (fused): per-graph segment-sum -> out1 = kv_sum + x_res (f32,
// also kept in LDS) -> att = (q/denom) . kv_sum for the graph's nodes.
// LDS: ksh/vsh 16KB, kvs 32x258 f32 (pad: stride%32==2 -> free 2-way,
// 8B-aligned for float2), kss 32x17 f32.
// =====================================================================
__device__ __forceinline__ int lbound(const int* __restrict__ a, int is64,
                                      int lo, int n, int key){
  int l = lo, h = n;
  while (l < h) { int m = (l + h) >> 1; if (getb(a, is64, m) < key) l = m + 1; else h = m; }
  return l;
}

__global__ __launch_bounds__(256) void k_segatt(
    const u16* __restrict__ xk, const u16* __restrict__ xv,
    const u16* __restrict__ xq, const float* __restrict__ xres,
    const int* __restrict__ batch, const int* __restrict__ flags,
    float* __restrict__ out1, u16* __restrict__ att, int N)
{
  __shared__ float ksh[4][512];
  __shared__ float vsh[4][512];
  __shared__ __align__(16) float kvs[32*258];
  __shared__ __align__(16) float kss[32*17];
  const int b = blockIdx.x, t = threadIdx.x;
  const int is64 = flags[0];
  const int lo = lbound(batch, is64, 0, N, b);
  const int hi = lbound(batch, is64, lo, N, b + 1);

  float kv[2][16];
#pragma unroll
  for (int r = 0; r < 2; r++)
#pragma unroll
    for (int v = 0; v < 16; v++) kv[r][v] = 0.f;
  float ks0 = 0.f, ks1 = 0.f;
  const int nh = t >> 3, hp = t & 7;

  // ---- phase 1: segment sums ----
  for (int base = lo; base < hi; base += 4) {
    __syncthreads();
    {
      int j = t >> 6, e8 = (t & 63)*8;
      uint4 K4 = make_uint4(0u,0u,0u,0u), V4 = make_uint4(0u,0u,0u,0u);
      int node = base + j;
      if (node < hi) {
        K4 = *(const uint4*)(xk + (size_t)node*512 + e8);
        V4 = *(const uint4*)(xv + (size_t)node*512 + e8);
      }
      float kf[8], vf[8]; unpack8(K4, kf); unpack8(V4, vf);
#pragma unroll
      for (int i = 0; i < 8; i++) { ksh[j][e8+i] = kf[i]; vsh[j][e8+i] = vf[i]; }
    }
    __syncthreads();
#pragma unroll
    for (int j = 0; j < 4; j++) {
      float k0 = ksh[j][nh*16 + 2*hp], k1 = ksh[j][nh*16 + 2*hp + 1];
      float4 V0 = *(const float4*)&vsh[j][nh*16];
      float4 V1 = *(const float4*)&vsh[j][nh*16 + 4];
      float4 V2 = *(const float4*)&vsh[j][nh*16 + 8];
      float4 V3 = *(const float4*)&vsh[j][nh*16 + 12];
      float vv[16] = {V0.x,V0.y,V0.z,V0.w,V1.x,V1.y,V1.z,V1.w,
                      V2.x,V2.y,V2.z,V2.w,V3.x,V3.y,V3.z,V3.w};
#pragma unroll
      for (int v = 0; v < 16; v++) {
        kv[0][v] = fmaf(k0, vv[v], kv[0][v]);
        kv[1][v] = fmaf(k1, vv[v], kv[1][v]);
      }
      ks0 += ksh[j][2*t]; ks1 += ksh[j][2*t + 1];
    }
  }
  // ensure phase-1 LDS reads done before any reuse hazards; also makes
  // kss/kvs writes safe to publish with one barrier below.
  kss[nh*17 + 2*hp]     = ks0;
  kss[nh*17 + 2*hp + 1] = ks1;

  // ---- phase 2: out1 = kv + xres (global f32 + LDS copy) ----
#pragma unroll
  for (int r = 0; r < 2; r++) {
    int h = 2*hp + r;
    size_t idx = ((size_t)(b*32 + nh)*16 + h)*16;
    const float* xp = xres + idx;
    float4 X0 = *(const float4*)xp;
    float4 X1 = *(const float4*)(xp + 4);
    float4 X2 = *(const float4*)(xp + 8);
    float4 X3 = *(const float4*)(xp + 12);
    float xf[16] = {X0.x,X0.y,X0.z,X0.w,X1.x,X1.y,X1.z,X1.w,
                    X2.x,X2.y,X2.z,X2.w,X3.x,X3.y,X3.z,X3.w};
    float o[16];
#pragma unroll
    for (int j = 0; j < 16; j++) o[j] = kv[r][j] + xf[j];
    float* op = out1 + idx;
    *(float4*)op        = make_float4(o[0],o[1],o[2],o[3]);
    *(float4*)(op + 4)  = make_float4(o[4],o[5],o[6],o[7]);
    *(float4*)(op + 8)  = make_float4(o[8],o[9],o[10],o[11]);
    *(float4*)(op + 12) = make_float4(o[12],o[13],o[14],o[15]);
    float* lp = &kvs[nh*258 + h*16];
#pragma unroll
    for (int j = 0; j < 8; j++)
      *(float2*)&lp[2*j] = make_float2(o[2*j], o[2*j+1]);
  }
  __syncthreads();

  // ---- phase 3: att for this graph's nodes ----
  const int nh2 = t & 31, ns = t >> 5;   // 8 nodes / iteration
  for (int n0 = lo; n0 < hi; n0 += 8) {
    int node = n0 + ns;
    if (node >= hi) continue;
    const u16* qp = xq + (size_t)node*512 + nh2*16;
    uint4 Q0 = *(const uint4*)qp;
    uint4 Q1 = *(const uint4*)(qp + 8);
    float q[16]; unpack8(Q0, q); unpack8(Q1, q + 8);
    const float* ksp = &kss[nh2*17];
    float denom = 0.f;
#pragma unroll
    for (int i = 0; i < 16; i++) denom = fmaf(q[i], ksp[i], denom);
    float inv = 1.0f / fmaxf(denom, 1e-20f);
    float a[16];
#pragma unroll
    for (int v = 0; v < 16; v++) a[v] = 0.f;
    const float* kvp = &kvs[nh2*258];
#pragma unroll
    for (int h = 0; h < 16; h++) {
      float qh = q[h] * inv;
#pragma unroll
      for (int j = 0; j < 8; j++) {
        float2 w = *(const float2*)&kvp[h*16 + 2*j];
        a[2*j]   = fmaf(qh, w.x, a[2*j]);
        a[2*j+1] = fmaf(qh, w.y, a[2*j+1]);
      }
    }
    u32 p[8];
#pragma unroll
    for (int j = 0; j < 8; j++) p[j] = pack2(a[2*j], a[2*j+1]);
    u16* dst = att + (size_t)node*512 + nh2*16;
    *(uint4*)dst       = make_uint4(p[0],p[1],p[2],p[3]);
    *(uint4*)(dst + 8) = make_uint4(p[4],p[5],p[6],p[7]);
  }
}

// =====================================================================
// K5 (MFMA): out0 = exp(log_scale) * (att @ w_post^T + b_post), K=512.
// =====================================================================
__global__ __launch_bounds__(256) void k_post(
    const u16* __restrict__ att, const float* __restrict__ wpost,
    const float* __restrict__ bpost, const float* __restrict__ ls,
    float* __restrict__ out0, int N, int nbm)
{
  __shared__ __align__(16) u16 As[64*40];
  __shared__ __align__(16) u16 Bs[64*40];
  const int t = threadIdx.x;
  const int bm = blockIdx.x % nbm;
  const int bn = blockIdx.x / nbm;          // 0..3
  const int m_base = bm*64, n_base = bn*64;
  const int w = t >> 6, lane = t & 63;
  const int wm = (w >> 1)*32, wn = (w & 1)*32;
  const int fr = lane & 15, fk = lane >> 4;
  const int srow = t >> 2, scol = (t & 3)*8;

  v4f acc[2][2];
#pragma unroll
  for (int i = 0; i < 2; i++)
#pragma unroll
    for (int j = 0; j < 2; j++) acc[i][j] = (v4f){0.f,0.f,0.f,0.f};

  for (int k0 = 0; k0 < 512; k0 += 32) {
    __syncthreads();
    {
      int gm = m_base + srow;
      uint4 av = make_uint4(0u,0u,0u,0u);
      if (gm < N) av = *(const uint4*)(att + (size_t)gm*512 + k0 + scol);
      *(uint4*)&As[srow*40 + scol] = av;
      uint4 bv = loadpack8(wpost + (size_t)(n_base + srow)*512 + k0 + scol);
      *(uint4*)&Bs[srow*40 + scol] = bv;
    }
    __syncthreads();
    v8s a0 = *(const v8s*)&As[(wm      + fr)*40 + fk*8];
    v8s a1 = *(const v8s*)&As[(wm + 16 + fr)*40 + fk*8];
    v8s b0 = *(const v8s*)&Bs[(wn      + fr)*40 + fk*8];
    v8s b1 = *(const v8s*)&Bs[(wn + 16 + fr)*40 + fk*8];
    acc[0][0] = __builtin_amdgcn_mfma_f32_16x16x32_bf16(a0,b0,acc[0][0],0,0,0);
    acc[0][1] = __builtin_amdgcn_mfma_f32_16x16x32_bf16(a0,b1,acc[0][1],0,0,0);
    acc[1][0] = __builtin_amdgcn_mfma_f32_16x16x32_bf16(a1,b0,acc[1][0],0,0,0);
    acc[1][1] = __builtin_amdgcn_mfma_f32_16x16x32_bf16(a1,b1,acc[1][1],0,0,0);
  }
#pragma unroll
  for (int nj = 0; nj < 2; nj++) {
    int col = n_base + wn + nj*16 + fr;
    float bpv = bpost[col];
    float e   = __expf(ls[col]);
#pragma unroll
    for (int mi = 0; mi < 2; mi++) {
#pragma unroll
      for (int r = 0; r < 4; r++) {
        int row = m_base + wm + mi*16 + fk*4 + r;
        if (row < N) out0[(size_t)row*256 + col] = e*(acc[mi][nj][r] + bpv);
      }
    }
  }
}

// =====================================================================
extern "C" void kernel_launch(void* const* d_in, const int* in_sizes, int n_in,
                              void* d_out, int out_size, void* d_ws, size_t ws_size,
                              hipStream_t stream)
{
  const float* x     = (const float*)d_in[0];
  const float* xres  = (const float*)d_in[1];
  const int*   batch = (const int*)d_in[2];
  const float* wpre  = (const float*)d_in[4];
  const float* bpre  = (const float*)d_in[5];
  const float* wq    = (const float*)d_in[6];
  const float* wk    = (const float*)d_in[7];
  const float* wv    = (const float*)d_in[8];
  const float* wpost = (const float*)d_in[9];
  const float* bpost = (const float*)d_in[10];
  const float* ls    = (const float*)d_in[11];

  const int N = in_sizes[0] / 256;     // 20000 nodes
  const int B = in_sizes[1] / 8192;    // 1024 graphs
  const int nbm = (N + 63) / 64;       // 313 row tiles

  char* ws = (char*)d_ws;
  size_t off = 0;
  int*   flags = (int*)(ws + off); off += 256;
  float* y     = (float*)(ws + off);                           // reused for att
  u16*   att   = (u16*)(ws + off);  off += (size_t)N * 1024;
  u16*   q     = (u16*)(ws + off);  off += (size_t)N * 1024;
  u16*   kten  = (u16*)(ws + off);  off += (size_t)N * 1024;
  u16*   vten  = (u16*)(ws + off);  off += (size_t)N * 1024;

  float* out0 = (float*)d_out;
  float* out1 = out0 + (size_t)N * 256;

  k_detect<<<1,              256, 0, stream>>>(batch, N, flags);
  k_pre   <<<nbm * 4,        256, 0, stream>>>(x, wpre, bpre, y, N, nbm);
  k_gnqkv <<<(N + 31) / 32,  256, 0, stream>>>(y, wq, wk, wv, q, kten, vten, N);
  k_segatt<<<B,              256, 0, stream>>>(kten, vten, q, xres, batch, flags,
                                               out1, att, N);
  k_post  <<<nbm * 4,        256, 0, stream>>>(att, wpost, bpost, ls, out0, N, nbm);
}

// Round 6
// 138.366 us; speedup vs baseline: 2.9663x; 1.3505x over previous
//
#include <hip/hip_runtime.h>
#include <stdint.h>

typedef unsigned int u32;
typedef unsigned short u16;
typedef __attribute__((ext_vector_type(8))) short v8s;   // 8 bf16 (4 VGPRs)
typedef __attribute__((ext_vector_type(4))) float v4f;   // 4 f32 acc

#define GN_EPS 1e-5f

// ---------- bf16 helpers (intermediates in ws are bf16) ----------
__device__ __forceinline__ float bflo(u32 u){ return __uint_as_float(u << 16); }
__device__ __forceinline__ float bfhi(u32 u){ return __uint_as_float(u & 0xffff0000u); }
__device__ __forceinline__ u16 f2bf(float f){
  u32 x = __float_as_uint(f);
  u32 r = (x + 0x7fffu + ((x >> 16) & 1u)) >> 16;   // RNE
  return (u16)r;
}
__device__ __forceinline__ u32 pack2(float a, float b){
  return (u32)f2bf(a) | ((u32)f2bf(b) << 16);
}
__device__ __forceinline__ void unpack8(const uint4 u, float* f){
  f[0]=bflo(u.x); f[1]=bfhi(u.x); f[2]=bflo(u.y); f[3]=bfhi(u.y);
  f[4]=bflo(u.z); f[5]=bfhi(u.z); f[6]=bflo(u.w); f[7]=bfhi(u.w);
}
// load 8 f32, return packed bf16 (4 u32)
__device__ __forceinline__ uint4 loadpack8(const float* __restrict__ p){
  float4 a = *(const float4*)p, b = *(const float4*)(p + 4);
  return make_uint4(pack2(a.x,a.y),pack2(a.z,a.w),pack2(b.x,b.y),pack2(b.z,b.w));
}

// batch accessor: int32 or int64 (little-endian low word)
__device__ __forceinline__ int getb(const int* __restrict__ b, int is64, int i){
  return b[is64 ? 2*i : i];
}

// =====================================================================
// K0: detect batch int-width (parallel). int64 viewed as int32 =
// [v,0,v,0,..] -> non-monotone once any v>0. flags[0] pre-zeroed by
// hipMemsetAsync; blocks atomicOr a 1 on violation.
// =====================================================================
__global__ __launch_bounds__(256) void k_detect(
    const int* __restrict__ batch, int n, int* __restrict__ flags)
{
  int i = blockIdx.x*256 + threadIdx.x;
  int bad = 0;
  if (i < n - 1 && batch[i] > batch[i + 1]) bad = 1;
  if (__builtin_amdgcn_ballot_w64(bad) != 0 && (threadIdx.x & 63) == 0)
    atomicOr(&flags[0], 1);
}

// =====================================================================
// K1 (MFMA): y = x @ w_pre^T + b_pre, f32 out. 64x64 tile, 4 waves 2x2.
// =====================================================================
__global__ __launch_bounds__(256) void k_pre(
    const float* __restrict__ x, const float* __restrict__ wpre,
    const float* __restrict__ bpre, float* __restrict__ y, int N, int nbm)
{
  __shared__ __align__(16) u16 As[64*40];
  __shared__ __align__(16) u16 Bs[64*40];
  const int t = threadIdx.x;
  const int bm = blockIdx.x % nbm;
  const int bn = blockIdx.x / nbm;          // 0..3
  const int m_base = bm*64, n_base = bn*64;
  const int w = t >> 6, lane = t & 63;
  const int wm = (w >> 1)*32, wn = (w & 1)*32;
  const int fr = lane & 15, fk = lane >> 4;
  const int srow = t >> 2, scol = (t & 3)*8;

  v4f acc[2][2];
#pragma unroll
  for (int i = 0; i < 2; i++)
#pragma unroll
    for (int j = 0; j < 2; j++) acc[i][j] = (v4f){0.f,0.f,0.f,0.f};

  for (int k0 = 0; k0 < 256; k0 += 32) {
    __syncthreads();
    {
      int gm = m_base + srow;
      uint4 av = make_uint4(0u,0u,0u,0u);
      if (gm < N) av = loadpack8(x + (size_t)gm*256 + k0 + scol);
      *(uint4*)&As[srow*40 + scol] = av;
      uint4 bv = loadpack8(wpre + (size_t)(n_base + srow)*256 + k0 + scol);
      *(uint4*)&Bs[srow*40 + scol] = bv;
    }
    __syncthreads();
    v8s a0 = *(const v8s*)&As[(wm      + fr)*40 + fk*8];
    v8s a1 = *(const v8s*)&As[(wm + 16 + fr)*40 + fk*8];
    v8s b0 = *(const v8s*)&Bs[(wn      + fr)*40 + fk*8];
    v8s b1 = *(const v8s*)&Bs[(wn + 16 + fr)*40 + fk*8];
    acc[0][0] = __builtin_amdgcn_mfma_f32_16x16x32_bf16(a0,b0,acc[0][0],0,0,0);
    acc[0][1] = __builtin_amdgcn_mfma_f32_16x16x32_bf16(a0,b1,acc[0][1],0,0,0);
    acc[1][0] = __builtin_amdgcn_mfma_f32_16x16x32_bf16(a1,b0,acc[1][0],0,0,0);
    acc[1][1] = __builtin_amdgcn_mfma_f32_16x16x32_bf16(a1,b1,acc[1][1],0,0,0);
  }
#pragma unroll
  for (int nj = 0; nj < 2; nj++) {
    int col = n_base + wn + nj*16 + fr;
    float bpv = bpre[col];
#pragma unroll
    for (int mi = 0; mi < 2; mi++) {
#pragma unroll
      for (int r = 0; r < 4; r++) {
        int row = m_base + wm + mi*16 + fk*4 + r;
        if (row < N) y[(size_t)row*256 + col] = acc[mi][nj][r] + bpv;
      }
    }
  }
}

// =====================================================================
// K2 (restructured): block = (group g, 256-node chunk). Stage only g's
// weights (3*512 f32 = 6KB) once; thread = node. Weight reads are
// wave-uniform broadcasts -> zero bank conflicts, zero inner barriers.
// =====================================================================
__global__ __launch_bounds__(256) void k_gnqkv(
    const float* __restrict__ y, const float* __restrict__ wq,
    const float* __restrict__ wk, const float* __restrict__ wv,
    u16* __restrict__ qo, u16* __restrict__ ko, u16* __restrict__ vo, int N)
{
  __shared__ __align__(16) float wL[3*512];   // [tensor][s*16+o][i] for group g
  const int t = threadIdx.x;
  const int g = blockIdx.x & 15;
  const int c = blockIdx.x >> 4;
  {
    const float* srcs[3] = {wq, wk, wv};
#pragma unroll
    for (int tz = 0; tz < 3; tz++) {
      wL[tz*512 + t]       = srcs[tz][g*512 + t];
      wL[tz*512 + t + 256] = srcs[tz][g*512 + t + 256];
    }
  }
  __syncthreads();
  const int node = c*256 + t;
  if (node >= N) return;

  // load this (node, group)'s 16 y values + GroupNorm in registers
  const float* yp = y + (size_t)node*256 + g*16;
  float4 v0 = *(const float4*)yp;
  float4 v1 = *(const float4*)(yp + 4);
  float4 v2 = *(const float4*)(yp + 8);
  float4 v3 = *(const float4*)(yp + 12);
  float a[16] = {v0.x,v0.y,v0.z,v0.w, v1.x,v1.y,v1.z,v1.w,
                 v2.x,v2.y,v2.z,v2.w, v3.x,v3.y,v3.z,v3.w};
  float mu = 0.f;
#pragma unroll
  for (int i = 0; i < 16; i++) mu += a[i];
  mu *= 0.0625f;
  float s2 = 0.f;
#pragma unroll
  for (int i = 0; i < 16; i++) { float d = a[i]-mu; s2 = fmaf(d,d,s2); }
  float inv = rsqrtf(s2*0.0625f + GN_EPS);
  float yn[16];
#pragma unroll
  for (int i = 0; i < 16; i++) yn[i] = (a[i]-mu)*inv;

  u16* outs[3] = {qo, ko, vo};
#pragma unroll
  for (int tz = 0; tz < 3; tz++) {
#pragma unroll
    for (int s = 0; s < 2; s++) {
      u32 p[8];
#pragma unroll
      for (int o = 0; o < 16; o++) {
        const float* row = &wL[tz*512 + (s*16 + o)*16];
        float4 W0 = *(const float4*)row;
        float4 W1 = *(const float4*)(row + 4);
        float4 W2 = *(const float4*)(row + 8);
        float4 W3 = *(const float4*)(row + 12);
        float w[16] = {W0.x,W0.y,W0.z,W0.w,W1.x,W1.y,W1.z,W1.w,
                       W2.x,W2.y,W2.z,W2.w,W3.x,W3.y,W3.z,W3.w};
        float d = 0.f;
#pragma unroll
        for (int i = 0; i < 16; i++) d = fmaf(yn[i], w[i], d);
        if (tz < 2) d = __expf(d*0.25f);
        if (o & 1) p[o>>1] |= (u32)f2bf(d) << 16;
        else       p[o>>1]  = (u32)f2bf(d);
      }
      u16* dst = outs[tz] + (size_t)node*512 + g*32 + s*16;
      *(uint4*)dst       = make_uint4(p[0],p[1],p[2],p[3]);
      *(uint4*)(dst + 8) = make_uint4(p[4],p[5],p[6],p[7]);
    }
  }
}

// =====================================================================
// K3 (fused): per-graph segment-sum -> out1 = kv_sum + x_res (f32,
// also kept in LDS) -> att = (q/denom) . kv_sum for the graph's nodes.
// =====================================================================
__device__ __forceinline__ int lbound(const int* __restrict__ a, int is64,
                                      int lo, int n, int key){
  int l = lo, h = n;
  while (l < h) { int m = (l + h) >> 1; if (getb(a, is64, m) < key) l = m + 1; else h = m; }
  return l;
}

__global__ __launch_bounds__(256) void k_segatt(
    const u16* __restrict__ xk, const u16* __restrict__ xv,
    const u16* __restrict__ xq, const float* __restrict__ xres,
    const int* __restrict__ batch, const int* __restrict__ flags,
    float* __restrict__ out1, u16* __restrict__ att, int N)
{
  __shared__ float ksh[4][512];
  __shared__ float vsh[4][512];
  __shared__ __align__(16) float kvs[32*258];
  __shared__ __align__(16) float kss[32*17];
  const int b = blockIdx.x, t = threadIdx.x;
  const int is64 = flags[0];
  const int lo = lbound(batch, is64, 0, N, b);
  const int hi = lbound(batch, is64, lo, N, b + 1);

  float kv[2][16];
#pragma unroll
  for (int r = 0; r < 2; r++)
#pragma unroll
    for (int v = 0; v < 16; v++) kv[r][v] = 0.f;
  float ks0 = 0.f, ks1 = 0.f;
  const int nh = t >> 3, hp = t & 7;

  // ---- phase 1: segment sums ----
  for (int base = lo; base < hi; base += 4) {
    __syncthreads();
    {
      int j = t >> 6, e8 = (t & 63)*8;
      uint4 K4 = make_uint4(0u,0u,0u,0u), V4 = make_uint4(0u,0u,0u,0u);
      int node = base + j;
      if (node < hi) {
        K4 = *(const uint4*)(xk + (size_t)node*512 + e8);
        V4 = *(const uint4*)(xv + (size_t)node*512 + e8);
      }
      float kf[8], vf[8]; unpack8(K4, kf); unpack8(V4, vf);
#pragma unroll
      for (int i = 0; i < 8; i++) { ksh[j][e8+i] = kf[i]; vsh[j][e8+i] = vf[i]; }
    }
    __syncthreads();
#pragma unroll
    for (int j = 0; j < 4; j++) {
      float k0 = ksh[j][nh*16 + 2*hp], k1 = ksh[j][nh*16 + 2*hp + 1];
      float4 V0 = *(const float4*)&vsh[j][nh*16];
      float4 V1 = *(const float4*)&vsh[j][nh*16 + 4];
      float4 V2 = *(const float4*)&vsh[j][nh*16 + 8];
      float4 V3 = *(const float4*)&vsh[j][nh*16 + 12];
      float vv[16] = {V0.x,V0.y,V0.z,V0.w,V1.x,V1.y,V1.z,V1.w,
                      V2.x,V2.y,V2.z,V2.w,V3.x,V3.y,V3.z,V3.w};
#pragma unroll
      for (int v = 0; v < 16; v++) {
        kv[0][v] = fmaf(k0, vv[v], kv[0][v]);
        kv[1][v] = fmaf(k1, vv[v], kv[1][v]);
      }
      ks0 += ksh[j][2*t]; ks1 += ksh[j][2*t + 1];
    }
  }
  kss[nh*17 + 2*hp]     = ks0;
  kss[nh*17 + 2*hp + 1] = ks1;

  // ---- phase 2: out1 = kv + xres (global f32 + LDS copy) ----
#pragma unroll
  for (int r = 0; r < 2; r++) {
    int h = 2*hp + r;
    size_t idx = ((size_t)(b*32 + nh)*16 + h)*16;
    const float* xp = xres + idx;
    float4 X0 = *(const float4*)xp;
    float4 X1 = *(const float4*)(xp + 4);
    float4 X2 = *(const float4*)(xp + 8);
    float4 X3 = *(const float4*)(xp + 12);
    float xf[16] = {X0.x,X0.y,X0.z,X0.w,X1.x,X1.y,X1.z,X1.w,
                    X2.x,X2.y,X2.z,X2.w,X3.x,X3.y,X3.z,X3.w};
    float o[16];
#pragma unroll
    for (int j = 0; j < 16; j++) o[j] = kv[r][j] + xf[j];
    float* op = out1 + idx;
    *(float4*)op        = make_float4(o[0],o[1],o[2],o[3]);
    *(float4*)(op + 4)  = make_float4(o[4],o[5],o[6],o[7]);
    *(float4*)(op + 8)  = make_float4(o[8],o[9],o[10],o[11]);
    *(float4*)(op + 12) = make_float4(o[12],o[13],o[14],o[15]);
    float* lp = &kvs[nh*258 + h*16];
#pragma unroll
    for (int j = 0; j < 8; j++)
      *(float2*)&lp[2*j] = make_float2(o[2*j], o[2*j+1]);
  }
  __syncthreads();

  // ---- phase 3: att for this graph's nodes ----
  const int nh2 = t & 31, ns = t >> 5;   // 8 nodes / iteration
  for (int n0 = lo; n0 < hi; n0 += 8) {
    int node = n0 + ns;
    if (node >= hi) continue;
    const u16* qp = xq + (size_t)node*512 + nh2*16;
    uint4 Q0 = *(const uint4*)qp;
    uint4 Q1 = *(const uint4*)(qp + 8);
    float q[16]; unpack8(Q0, q); unpack8(Q1, q + 8);
    const float* ksp = &kss[nh2*17];
    float denom = 0.f;
#pragma unroll
    for (int i = 0; i < 16; i++) denom = fmaf(q[i], ksp[i], denom);
    float inv = 1.0f / fmaxf(denom, 1e-20f);
    float a[16];
#pragma unroll
    for (int v = 0; v < 16; v++) a[v] = 0.f;
    const float* kvp = &kvs[nh2*258];
#pragma unroll
    for (int h = 0; h < 16; h++) {
      float qh = q[h] * inv;
#pragma unroll
      for (int j = 0; j < 8; j++) {
        float2 w = *(const float2*)&kvp[h*16 + 2*j];
        a[2*j]   = fmaf(qh, w.x, a[2*j]);
        a[2*j+1] = fmaf(qh, w.y, a[2*j+1]);
      }
    }
    u32 p[8];
#pragma unroll
    for (int j = 0; j < 8; j++) p[j] = pack2(a[2*j], a[2*j+1]);
    u16* dst = att + (size_t)node*512 + nh2*16;
    *(uint4*)dst       = make_uint4(p[0],p[1],p[2],p[3]);
    *(uint4*)(dst + 8) = make_uint4(p[4],p[5],p[6],p[7]);
  }
}

// =====================================================================
// K5 (MFMA): out0 = exp(log_scale) * (att @ w_post^T + b_post), K=512.
// =====================================================================
__global__ __launch_bounds__(256) void k_post(
    const u16* __restrict__ att, const float* __restrict__ wpost,
    const float* __restrict__ bpost, const float* __restrict__ ls,
    float* __restrict__ out0, int N, int nbm)
{
  __shared__ __align__(16) u16 As[64*40];
  __shared__ __align__(16) u16 Bs[64*40];
  const int t = threadIdx.x;
  const int bm = blockIdx.x % nbm;
  const int bn = blockIdx.x / nbm;          // 0..3
  const int m_base = bm*64, n_base = bn*64;
  const int w = t >> 6, lane = t & 63;
  const int wm = (w >> 1)*32, wn = (w & 1)*32;
  const int fr = lane & 15, fk = lane >> 4;
  const int srow = t >> 2, scol = (t & 3)*8;

  v4f acc[2][2];
#pragma unroll
  for (int i = 0; i < 2; i++)
#pragma unroll
    for (int j = 0; j < 2; j++) acc[i][j] = (v4f){0.f,0.f,0.f,0.f};

  for (int k0 = 0; k0 < 512; k0 += 32) {
    __syncthreads();
    {
      int gm = m_base + srow;
      uint4 av = make_uint4(0u,0u,0u,0u);
      if (gm < N) av = *(const uint4*)(att + (size_t)gm*512 + k0 + scol);
      *(uint4*)&As[srow*40 + scol] = av;
      uint4 bv = loadpack8(wpost + (size_t)(n_base + srow)*512 + k0 + scol);
      *(uint4*)&Bs[srow*40 + scol] = bv;
    }
    __syncthreads();
    v8s a0 = *(const v8s*)&As[(wm      + fr)*40 + fk*8];
    v8s a1 = *(const v8s*)&As[(wm + 16 + fr)*40 + fk*8];
    v8s b0 = *(const v8s*)&Bs[(wn      + fr)*40 + fk*8];
    v8s b1 = *(const v8s*)&Bs[(wn + 16 + fr)*40 + fk*8];
    acc[0][0] = __builtin_amdgcn_mfma_f32_16x16x32_bf16(a0,b0,acc[0][0],0,0,0);
    acc[0][1] = __builtin_amdgcn_mfma_f32_16x16x32_bf16(a0,b1,acc[0][1],0,0,0);
    acc[1][0] = __builtin_amdgcn_mfma_f32_16x16x32_bf16(a1,b0,acc[1][0],0,0,0);
    acc[1][1] = __builtin_amdgcn_mfma_f32_16x16x32_bf16(a1,b1,acc[1][1],0,0,0);
  }
#pragma unroll
  for (int nj = 0; nj < 2; nj++) {
    int col = n_base + wn + nj*16 + fr;
    float bpv = bpost[col];
    float e   = __expf(ls[col]);
#pragma unroll
    for (int mi = 0; mi < 2; mi++) {
#pragma unroll
      for (int r = 0; r < 4; r++) {
        int row = m_base + wm + mi*16 + fk*4 + r;
        if (row < N) out0[(size_t)row*256 + col] = e*(acc[mi][nj][r] + bpv);
      }
    }
  }
}

// =====================================================================
extern "C" void kernel_launch(void* const* d_in, const int* in_sizes, int n_in,
                              void* d_out, int out_size, void* d_ws, size_t ws_size,
                              hipStream_t stream)
{
  const float* x     = (const float*)d_in[0];
  const float* xres  = (const float*)d_in[1];
  const int*   batch = (const int*)d_in[2];
  const float* wpre  = (const float*)d_in[4];
  const float* bpre  = (const float*)d_in[5];
  const float* wq    = (const float*)d_in[6];
  const float* wk    = (const float*)d_in[7];
  const float* wv    = (const float*)d_in[8];
  const float* wpost = (const float*)d_in[9];
  const float* bpost = (const float*)d_in[10];
  const float* ls    = (const float*)d_in[11];

  const int N = in_sizes[0] / 256;     // 20000 nodes
  const int B = in_sizes[1] / 8192;    // 1024 graphs
  const int nbm = (N + 63) / 64;       // 313 row tiles
  const int nchunk = (N + 255) / 256;  // 79 node chunks

  char* ws = (char*)d_ws;
  size_t off = 0;
  int*   flags = (int*)(ws + off); off += 256;
  float* y     = (float*)(ws + off);                           // reused for att
  u16*   att   = (u16*)(ws + off);  off += (size_t)N * 1024;
  u16*   q     = (u16*)(ws + off);  off += (size_t)N * 1024;
  u16*   kten  = (u16*)(ws + off);  off += (size_t)N * 1024;
  u16*   vten  = (u16*)(ws + off);  off += (size_t)N * 1024;

  float* out0 = (float*)d_out;
  float* out1 = out0 + (size_t)N * 256;

  hipMemsetAsync(flags, 0, 4, stream);
  k_detect<<<nchunk,         256, 0, stream>>>(batch, N, flags);
  k_pre   <<<nbm * 4,        256, 0, stream>>>(x, wpre, bpre, y, N, nbm);
  k_gnqkv <<<nchunk * 16,    256, 0, stream>>>(y, wq, wk, wv, q, kten, vten, N);
  k_segatt<<<B,              256, 0, stream>>>(kten, vten, q, xres, batch, flags,
                                               out1, att, N);
  k_post  <<<nbm * 4,        256, 0, stream>>>(att, wpost, bpost, ls, out0, N, nbm);
}

// Round 7
// 135.936 us; speedup vs baseline: 3.0193x; 1.0179x over previous
//
#include <hip/hip_runtime.h>
#include <stdint.h>

typedef unsigned int u32;
typedef unsigned short u16;
typedef __attribute__((ext_vector_type(8))) short v8s;   // 8 bf16 (4 VGPRs)
typedef __attribute__((ext_vector_type(4))) float v4f;   // 4 f32 acc

#define GN_EPS 1e-5f

// ---------- bf16 helpers (intermediates in ws are bf16) ----------
__device__ __forceinline__ float bflo(u32 u){ return __uint_as_float(u << 16); }
__device__ __forceinline__ float bfhi(u32 u){ return __uint_as_float(u & 0xffff0000u); }
__device__ __forceinline__ u16 f2bf(float f){
  u32 x = __float_as_uint(f);
  u32 r = (x + 0x7fffu + ((x >> 16) & 1u)) >> 16;   // RNE
  return (u16)r;
}
__device__ __forceinline__ u32 pack2(float a, float b){
  return (u32)f2bf(a) | ((u32)f2bf(b) << 16);
}
__device__ __forceinline__ void unpack8(const uint4 u, float* f){
  f[0]=bflo(u.x); f[1]=bfhi(u.x); f[2]=bflo(u.y); f[3]=bfhi(u.y);
  f[4]=bflo(u.z); f[5]=bfhi(u.z); f[6]=bflo(u.w); f[7]=bfhi(u.w);
}
// load 8 f32, return packed bf16 (4 u32)
__device__ __forceinline__ uint4 loadpack8(const float* __restrict__ p){
  float4 a = *(const float4*)p, b = *(const float4*)(p + 4);
  return make_uint4(pack2(a.x,a.y),pack2(a.z,a.w),pack2(b.x,b.y),pack2(b.z,b.w));
}

// batch accessor: int32 or int64 (little-endian low word)
__device__ __forceinline__ int getb(const int* __restrict__ b, int is64, int i){
  return b[is64 ? 2*i : i];
}

// =====================================================================
// K0: detect batch int-width (parallel). int64 viewed as int32 =
// [v,0,v,0,..] -> non-monotone once any v>0. flags[0] pre-zeroed.
// =====================================================================
__global__ __launch_bounds__(256) void k_detect(
    const int* __restrict__ batch, int n, int* __restrict__ flags)
{
  int i = blockIdx.x*256 + threadIdx.x;
  int bad = 0;
  if (i < n - 1 && batch[i] > batch[i + 1]) bad = 1;
  if (__builtin_amdgcn_ballot_w64(bad) != 0 && (threadIdx.x & 63) == 0)
    atomicOr(&flags[0], 1);
}

// =====================================================================
// K0b: CSR bounds. bounds[g] = first node of graph g; bounds[B] = N.
// Each node-thread fills the entries for graphs starting at it (incl.
// skipped empty graphs); last node fills the tail.
// =====================================================================
__global__ __launch_bounds__(256) void k_bounds(
    const int* __restrict__ batch, const int* __restrict__ flags,
    int N, int B, int* __restrict__ bounds)
{
  int i = blockIdx.x*256 + threadIdx.x;
  if (i >= N) return;
  const int is64 = flags[0];
  int b = getb(batch, is64, i);
  int prev = (i == 0) ? -1 : getb(batch, is64, i - 1);
  for (int g = prev + 1; g <= b; g++) bounds[g] = i;
  if (i == N - 1)
    for (int g = b + 1; g <= B; g++) bounds[g] = N;
}

// =====================================================================
// K1 (MFMA): y = x @ w_pre^T + b_pre, f32 out. 64x64 tile, 4 waves 2x2.
// =====================================================================
__global__ __launch_bounds__(256) void k_pre(
    const float* __restrict__ x, const float* __restrict__ wpre,
    const float* __restrict__ bpre, float* __restrict__ y, int N, int nbm)
{
  __shared__ __align__(16) u16 As[64*40];
  __shared__ __align__(16) u16 Bs[64*40];
  const int t = threadIdx.x;
  const int bm = blockIdx.x % nbm;
  const int bn = blockIdx.x / nbm;          // 0..3
  const int m_base = bm*64, n_base = bn*64;
  const int w = t >> 6, lane = t & 63;
  const int wm = (w >> 1)*32, wn = (w & 1)*32;
  const int fr = lane & 15, fk = lane >> 4;
  const int srow = t >> 2, scol = (t & 3)*8;

  v4f acc[2][2];
#pragma unroll
  for (int i = 0; i < 2; i++)
#pragma unroll
    for (int j = 0; j < 2; j++) acc[i][j] = (v4f){0.f,0.f,0.f,0.f};

  for (int k0 = 0; k0 < 256; k0 += 32) {
    __syncthreads();
    {
      int gm = m_base + srow;
      uint4 av = make_uint4(0u,0u,0u,0u);
      if (gm < N) av = loadpack8(x + (size_t)gm*256 + k0 + scol);
      *(uint4*)&As[srow*40 + scol] = av;
      uint4 bv = loadpack8(wpre + (size_t)(n_base + srow)*256 + k0 + scol);
      *(uint4*)&Bs[srow*40 + scol] = bv;
    }
    __syncthreads();
    v8s a0 = *(const v8s*)&As[(wm      + fr)*40 + fk*8];
    v8s a1 = *(const v8s*)&As[(wm + 16 + fr)*40 + fk*8];
    v8s b0 = *(const v8s*)&Bs[(wn      + fr)*40 + fk*8];
    v8s b1 = *(const v8s*)&Bs[(wn + 16 + fr)*40 + fk*8];
    acc[0][0] = __builtin_amdgcn_mfma_f32_16x16x32_bf16(a0,b0,acc[0][0],0,0,0);
    acc[0][1] = __builtin_amdgcn_mfma_f32_16x16x32_bf16(a0,b1,acc[0][1],0,0,0);
    acc[1][0] = __builtin_amdgcn_mfma_f32_16x16x32_bf16(a1,b0,acc[1][0],0,0,0);
    acc[1][1] = __builtin_amdgcn_mfma_f32_16x16x32_bf16(a1,b1,acc[1][1],0,0,0);
  }
#pragma unroll
  for (int nj = 0; nj < 2; nj++) {
    int col = n_base + wn + nj*16 + fr;
    float bpv = bpre[col];
#pragma unroll
    for (int mi = 0; mi < 2; mi++) {
#pragma unroll
      for (int r = 0; r < 4; r++) {
        int row = m_base + wm + mi*16 + fk*4 + r;
        if (row < N) y[(size_t)row*256 + col] = acc[mi][nj][r] + bpv;
      }
    }
  }
}

// =====================================================================
// K2: block = (group g, 256-node chunk). Weight reads wave-uniform.
// =====================================================================
__global__ __launch_bounds__(256) void k_gnqkv(
    const float* __restrict__ y, const float* __restrict__ wq,
    const float* __restrict__ wk, const float* __restrict__ wv,
    u16* __restrict__ qo, u16* __restrict__ ko, u16* __restrict__ vo, int N)
{
  __shared__ __align__(16) float wL[3*512];
  const int t = threadIdx.x;
  const int g = blockIdx.x & 15;
  const int c = blockIdx.x >> 4;
  {
    const float* srcs[3] = {wq, wk, wv};
#pragma unroll
    for (int tz = 0; tz < 3; tz++) {
      wL[tz*512 + t]       = srcs[tz][g*512 + t];
      wL[tz*512 + t + 256] = srcs[tz][g*512 + t + 256];
    }
  }
  __syncthreads();
  const int node = c*256 + t;
  if (node >= N) return;

  const float* yp = y + (size_t)node*256 + g*16;
  float4 v0 = *(const float4*)yp;
  float4 v1 = *(const float4*)(yp + 4);
  float4 v2 = *(const float4*)(yp + 8);
  float4 v3 = *(const float4*)(yp + 12);
  float a[16] = {v0.x,v0.y,v0.z,v0.w, v1.x,v1.y,v1.z,v1.w,
                 v2.x,v2.y,v2.z,v2.w, v3.x,v3.y,v3.z,v3.w};
  float mu = 0.f;
#pragma unroll
  for (int i = 0; i < 16; i++) mu += a[i];
  mu *= 0.0625f;
  float s2 = 0.f;
#pragma unroll
  for (int i = 0; i < 16; i++) { float d = a[i]-mu; s2 = fmaf(d,d,s2); }
  float inv = rsqrtf(s2*0.0625f + GN_EPS);
  float yn[16];
#pragma unroll
  for (int i = 0; i < 16; i++) yn[i] = (a[i]-mu)*inv;

  u16* outs[3] = {qo, ko, vo};
#pragma unroll
  for (int tz = 0; tz < 3; tz++) {
#pragma unroll
    for (int s = 0; s < 2; s++) {
      u32 p[8];
#pragma unroll
      for (int o = 0; o < 16; o++) {
        const float* row = &wL[tz*512 + (s*16 + o)*16];
        float4 W0 = *(const float4*)row;
        float4 W1 = *(const float4*)(row + 4);
        float4 W2 = *(const float4*)(row + 8);
        float4 W3 = *(const float4*)(row + 12);
        float w[16] = {W0.x,W0.y,W0.z,W0.w,W1.x,W1.y,W1.z,W1.w,
                       W2.x,W2.y,W2.z,W2.w,W3.x,W3.y,W3.z,W3.w};
        float d = 0.f;
#pragma unroll
        for (int i = 0; i < 16; i++) d = fmaf(yn[i], w[i], d);
        if (tz < 2) d = __expf(d*0.25f);
        if (o & 1) p[o>>1] |= (u32)f2bf(d) << 16;
        else       p[o>>1]  = (u32)f2bf(d);
      }
      u16* dst = outs[tz] + (size_t)node*512 + g*32 + s*16;
      *(uint4*)dst       = make_uint4(p[0],p[1],p[2],p[3]);
      *(uint4*)(dst + 8) = make_uint4(p[4],p[5],p[6],p[7]);
    }
  }
}

// =====================================================================
// K3 (rewritten): per-graph fused segment-sum + att.
// Phase 1 (no LDS, no barriers): wave w owns heads [8w,8w+8); loops all
//   graph nodes reading k/v direct from global (k contiguous 256B/wave,
//   v 8-lane broadcast rows). Thread (nh,hp) accumulates kv[2][16], ks.
// Phase 2: out1 = kv + xres (f32 global); kv -> LDS bf16, head stride
//   280 u16 (=140 dwords, %32==12 -> conflict-free b128 reads); ks->LDS.
// Phase 3: per (node, head): denom = q.ks; att = (q/denom) . kv_lds.
// =====================================================================
__global__ __launch_bounds__(256) void k_segatt(
    const u16* __restrict__ xk, const u16* __restrict__ xv,
    const u16* __restrict__ xq, const float* __restrict__ xres,
    const int* __restrict__ bounds,
    float* __restrict__ out1, u16* __restrict__ att, int N)
{
  __shared__ __align__(16) u16 kvs[32*280];   // 17.5 KB
  __shared__ float kss[32*17];                // 2.2 KB
  const int b = blockIdx.x, t = threadIdx.x;
  const int lo = bounds[b], hi = bounds[b+1];
  const int nh = t >> 3, hp = t & 7;

  float kv[2][16];
#pragma unroll
  for (int r = 0; r < 2; r++)
#pragma unroll
    for (int v = 0; v < 16; v++) kv[r][v] = 0.f;
  float ks0 = 0.f, ks1 = 0.f;

  // ---- phase 1: direct-from-global accumulation, no barriers ----
  const size_t koff = (size_t)nh*16 + 2*hp;   // this thread's k pair
  const size_t voff = (size_t)nh*16;          // this head's v row
  for (int node = lo; node < hi; node++) {
    u32 kw = *(const u32*)(xk + (size_t)node*512 + koff);
    uint4 V0 = *(const uint4*)(xv + (size_t)node*512 + voff);
    uint4 V1 = *(const uint4*)(xv + (size_t)node*512 + voff + 8);
    float k0 = bflo(kw), k1 = bfhi(kw);
    float vf[16]; unpack8(V0, vf); unpack8(V1, vf + 8);
    ks0 += k0; ks1 += k1;
#pragma unroll
    for (int v = 0; v < 16; v++) {
      kv[0][v] = fmaf(k0, vf[v], kv[0][v]);
      kv[1][v] = fmaf(k1, vf[v], kv[1][v]);
    }
  }
  kss[nh*17 + 2*hp]     = ks0;
  kss[nh*17 + 2*hp + 1] = ks1;

  // ---- phase 2: out1 = kv + xres; kv -> LDS (bf16) ----
#pragma unroll
  for (int r = 0; r < 2; r++) {
    int h = 2*hp + r;
    size_t idx = ((size_t)(b*32 + nh)*16 + h)*16;
    const float* xp = xres + idx;
    float4 X0 = *(const float4*)xp;
    float4 X1 = *(const float4*)(xp + 4);
    float4 X2 = *(const float4*)(xp + 8);
    float4 X3 = *(const float4*)(xp + 12);
    float xf[16] = {X0.x,X0.y,X0.z,X0.w,X1.x,X1.y,X1.z,X1.w,
                    X2.x,X2.y,X2.z,X2.w,X3.x,X3.y,X3.z,X3.w};
    float o[16];
#pragma unroll
    for (int j = 0; j < 16; j++) o[j] = kv[r][j] + xf[j];
    float* op = out1 + idx;
    *(float4*)op        = make_float4(o[0],o[1],o[2],o[3]);
    *(float4*)(op + 4)  = make_float4(o[4],o[5],o[6],o[7]);
    *(float4*)(op + 8)  = make_float4(o[8],o[9],o[10],o[11]);
    *(float4*)(op + 12) = make_float4(o[12],o[13],o[14],o[15]);
    u16* lp = &kvs[nh*280 + h*16];
    *(uint4*)lp       = make_uint4(pack2(o[0],o[1]),  pack2(o[2],o[3]),
                                   pack2(o[4],o[5]),  pack2(o[6],o[7]));
    *(uint4*)(lp + 8) = make_uint4(pack2(o[8],o[9]),  pack2(o[10],o[11]),
                                   pack2(o[12],o[13]),pack2(o[14],o[15]));
  }
  __syncthreads();

  // ---- phase 3: att for this graph's nodes ----
  const int nh2 = t & 31, ns = t >> 5;   // 8 nodes / iteration
  for (int n0 = lo; n0 < hi; n0 += 8) {
    int node = n0 + ns;
    if (node >= hi) continue;
    const u16* qp = xq + (size_t)node*512 + nh2*16;
    uint4 Q0 = *(const uint4*)qp;
    uint4 Q1 = *(const uint4*)(qp + 8);
    float q[16]; unpack8(Q0, q); unpack8(Q1, q + 8);
    const float* ksp = &kss[nh2*17];
    float denom = 0.f;
#pragma unroll
    for (int i = 0; i < 16; i++) denom = fmaf(q[i], ksp[i], denom);
    float inv = 1.0f / fmaxf(denom, 1e-20f);
    float a[16];
#pragma unroll
    for (int v = 0; v < 16; v++) a[v] = 0.f;
    const u16* kvp = &kvs[nh2*280];
#pragma unroll
    for (int h = 0; h < 16; h++) {
      float qh = q[h] * inv;
      uint4 W0 = *(const uint4*)(kvp + h*16);
      uint4 W1 = *(const uint4*)(kvp + h*16 + 8);
      float w[16]; unpack8(W0, w); unpack8(W1, w + 8);
#pragma unroll
      for (int v = 0; v < 16; v++) a[v] = fmaf(qh, w[v], a[v]);
    }
    u32 p[8];
#pragma unroll
    for (int j = 0; j < 8; j++) p[j] = pack2(a[2*j], a[2*j+1]);
    u16* dst = att + (size_t)node*512 + nh2*16;
    *(uint4*)dst       = make_uint4(p[0],p[1],p[2],p[3]);
    *(uint4*)(dst + 8) = make_uint4(p[4],p[5],p[6],p[7]);
  }
}

// =====================================================================
// K5 (MFMA): out0 = exp(log_scale) * (att @ w_post^T + b_post), K=512.
// =====================================================================
__global__ __launch_bounds__(256) void k_post(
    const u16* __restrict__ att, const float* __restrict__ wpost,
    const float* __restrict__ bpost, const float* __restrict__ ls,
    float* __restrict__ out0, int N, int nbm)
{
  __shared__ __align__(16) u16 As[64*40];
  __shared__ __align__(16) u16 Bs[64*40];
  const int t = threadIdx.x;
  const int bm = blockIdx.x % nbm;
  const int bn = blockIdx.x / nbm;          // 0..3
  const int m_base = bm*64, n_base = bn*64;
  const int w = t >> 6, lane = t & 63;
  const int wm = (w >> 1)*32, wn = (w & 1)*32;
  const int fr = lane & 15, fk = lane >> 4;
  const int srow = t >> 2, scol = (t & 3)*8;

  v4f acc[2][2];
#pragma unroll
  for (int i = 0; i < 2; i++)
#pragma unroll
    for (int j = 0; j < 2; j++) acc[i][j] = (v4f){0.f,0.f,0.f,0.f};

  for (int k0 = 0; k0 < 512; k0 += 32) {
    __syncthreads();
    {
      int gm = m_base + srow;
      uint4 av = make_uint4(0u,0u,0u,0u);
      if (gm < N) av = *(const uint4*)(att + (size_t)gm*512 + k0 + scol);
      *(uint4*)&As[srow*40 + scol] = av;
      uint4 bv = loadpack8(wpost + (size_t)(n_base + srow)*512 + k0 + scol);
      *(uint4*)&Bs[srow*40 + scol] = bv;
    }
    __syncthreads();
    v8s a0 = *(const v8s*)&As[(wm      + fr)*40 + fk*8];
    v8s a1 = *(const v8s*)&As[(wm + 16 + fr)*40 + fk*8];
    v8s b0 = *(const v8s*)&Bs[(wn      + fr)*40 + fk*8];
    v8s b1 = *(const v8s*)&Bs[(wn + 16 + fr)*40 + fk*8];
    acc[0][0] = __builtin_amdgcn_mfma_f32_16x16x32_bf16(a0,b0,acc[0][0],0,0,0);
    acc[0][1] = __builtin_amdgcn_mfma_f32_16x16x32_bf16(a0,b1,acc[0][1],0,0,0);
    acc[1][0] = __builtin_amdgcn_mfma_f32_16x16x32_bf16(a1,b0,acc[1][0],0,0,0);
    acc[1][1] = __builtin_amdgcn_mfma_f32_16x16x32_bf16(a1,b1,acc[1][1],0,0,0);
  }
#pragma unroll
  for (int nj = 0; nj < 2; nj++) {
    int col = n_base + wn + nj*16 + fr;
    float bpv = bpost[col];
    float e   = __expf(ls[col]);
#pragma unroll
    for (int mi = 0; mi < 2; mi++) {
#pragma unroll
      for (int r = 0; r < 4; r++) {
        int row = m_base + wm + mi*16 + fk*4 + r;
        if (row < N) out0[(size_t)row*256 + col] = e*(acc[mi][nj][r] + bpv);
      }
    }
  }
}

// =====================================================================
extern "C" void kernel_launch(void* const* d_in, const int* in_sizes, int n_in,
                              void* d_out, int out_size, void* d_ws, size_t ws_size,
                              hipStream_t stream)
{
  const float* x     = (const float*)d_in[0];
  const float* xres  = (const float*)d_in[1];
  const int*   batch = (const int*)d_in[2];
  const float* wpre  = (const float*)d_in[4];
  const float* bpre  = (const float*)d_in[5];
  const float* wq    = (const float*)d_in[6];
  const float* wk    = (const float*)d_in[7];
  const float* wv    = (const float*)d_in[8];
  const float* wpost = (const float*)d_in[9];
  const float* bpost = (const float*)d_in[10];
  const float* ls    = (const float*)d_in[11];

  const int N = in_sizes[0] / 256;     // 20000 nodes
  const int B = in_sizes[1] / 8192;    // 1024 graphs
  const int nbm = (N + 63) / 64;       // 313 row tiles
  const int nchunk = (N + 255) / 256;  // 79 node chunks

  char* ws = (char*)d_ws;
  size_t off = 0;
  int*   flags  = (int*)(ws + off); off += 256;
  int*   bounds = (int*)(ws + off); off += ((size_t)B + 64) * 4;
  float* y      = (float*)(ws + off);                          // reused for att
  u16*   att    = (u16*)(ws + off);  off += (size_t)N * 1024;
  u16*   q      = (u16*)(ws + off);  off += (size_t)N * 1024;
  u16*   kten   = (u16*)(ws + off);  off += (size_t)N * 1024;
  u16*   vten   = (u16*)(ws + off);  off += (size_t)N * 1024;

  float* out0 = (float*)d_out;
  float* out1 = out0 + (size_t)N * 256;

  hipMemsetAsync(flags, 0, 4, stream);
  k_detect<<<nchunk,         256, 0, stream>>>(batch, N, flags);
  k_bounds<<<nchunk,         256, 0, stream>>>(batch, flags, N, B, bounds);
  k_pre   <<<nbm * 4,        256, 0, stream>>>(x, wpre, bpre, y, N, nbm);
  k_gnqkv <<<nchunk * 16,    256, 0, stream>>>(y, wq, wk, wv, q, kten, vten, N);
  k_segatt<<<B,              256, 0, stream>>>(kten, vten, q, xres, bounds,
                                               out1, att, N);
  k_post  <<<nbm * 4,        256, 0, stream>>>(att, wpost, bpost, ls, out0, N, nbm);
}

// Round 8
// 135.173 us; speedup vs baseline: 3.0364x; 1.0056x over previous
//
#include <hip/hip_runtime.h>
#include <stdint.h>

typedef unsigned int u32;
typedef unsigned short u16;
typedef __attribute__((ext_vector_type(8))) short v8s;   // 8 bf16 (4 VGPRs)
typedef __attribute__((ext_vector_type(4))) float v4f;   // 4 f32 acc

#define GN_EPS 1e-5f

// ---------- bf16 helpers (intermediates in ws are bf16) ----------
__device__ __forceinline__ float bflo(u32 u){ return __uint_as_float(u << 16); }
__device__ __forceinline__ float bfhi(u32 u){ return __uint_as_float(u & 0xffff0000u); }
__device__ __forceinline__ u16 f2bf(float f){
  u32 x = __float_as_uint(f);
  u32 r = (x + 0x7fffu + ((x >> 16) & 1u)) >> 16;   // RNE
  return (u16)r;
}
__device__ __forceinline__ u32 pack2(float a, float b){
  return (u32)f2bf(a) | ((u32)f2bf(b) << 16);
}
__device__ __forceinline__ void unpack8(const uint4 u, float* f){
  f[0]=bflo(u.x); f[1]=bfhi(u.x); f[2]=bflo(u.y); f[3]=bfhi(u.y);
  f[4]=bflo(u.z); f[5]=bfhi(u.z); f[6]=bflo(u.w); f[7]=bfhi(u.w);
}
// load 8 f32, return packed bf16 (4 u32)
__device__ __forceinline__ uint4 loadpack8(const float* __restrict__ p){
  float4 a = *(const float4*)p, b = *(const float4*)(p + 4);
  return make_uint4(pack2(a.x,a.y),pack2(a.z,a.w),pack2(b.x,b.y),pack2(b.z,b.w));
}

// batch accessor: int32 or int64 (little-endian low word)
__device__ __forceinline__ int getb(const int* __restrict__ b, int is64, int i){
  return b[is64 ? 2*i : i];
}

// =====================================================================
// K0: detect batch int-width (parallel).
// =====================================================================
__global__ __launch_bounds__(256) void k_detect(
    const int* __restrict__ batch, int n, int* __restrict__ flags)
{
  int i = blockIdx.x*256 + threadIdx.x;
  int bad = 0;
  if (i < n - 1 && batch[i] > batch[i + 1]) bad = 1;
  if (__builtin_amdgcn_ballot_w64(bad) != 0 && (threadIdx.x & 63) == 0)
    atomicOr(&flags[0], 1);
}

// =====================================================================
// K0b: CSR bounds. bounds[g] = first node of graph g; bounds[B] = N.
// =====================================================================
__global__ __launch_bounds__(256) void k_bounds(
    const int* __restrict__ batch, const int* __restrict__ flags,
    int N, int B, int* __restrict__ bounds)
{
  int i = blockIdx.x*256 + threadIdx.x;
  if (i >= N) return;
  const int is64 = flags[0];
  int b = getb(batch, is64, i);
  int prev = (i == 0) ? -1 : getb(batch, is64, i - 1);
  for (int g = prev + 1; g <= b; g++) bounds[g] = i;
  if (i == N - 1)
    for (int g = b + 1; g <= B; g++) bounds[g] = N;
}

// =====================================================================
// K1 (MFMA): y = x @ w_pre^T + b_pre, f32 out. 64x64 tile, 4 waves 2x2.
// =====================================================================
__global__ __launch_bounds__(256) void k_pre(
    const float* __restrict__ x, const float* __restrict__ wpre,
    const float* __restrict__ bpre, float* __restrict__ y, int N, int nbm)
{
  __shared__ __align__(16) u16 As[64*40];
  __shared__ __align__(16) u16 Bs[64*40];
  const int t = threadIdx.x;
  const int bm = blockIdx.x % nbm;
  const int bn = blockIdx.x / nbm;          // 0..3
  const int m_base = bm*64, n_base = bn*64;
  const int w = t >> 6, lane = t & 63;
  const int wm = (w >> 1)*32, wn = (w & 1)*32;
  const int fr = lane & 15, fk = lane >> 4;
  const int srow = t >> 2, scol = (t & 3)*8;

  v4f acc[2][2];
#pragma unroll
  for (int i = 0; i < 2; i++)
#pragma unroll
    for (int j = 0; j < 2; j++) acc[i][j] = (v4f){0.f,0.f,0.f,0.f};

  for (int k0 = 0; k0 < 256; k0 += 32) {
    __syncthreads();
    {
      int gm = m_base + srow;
      uint4 av = make_uint4(0u,0u,0u,0u);
      if (gm < N) av = loadpack8(x + (size_t)gm*256 + k0 + scol);
      *(uint4*)&As[srow*40 + scol] = av;
      uint4 bv = loadpack8(wpre + (size_t)(n_base + srow)*256 + k0 + scol);
      *(uint4*)&Bs[srow*40 + scol] = bv;
    }
    __syncthreads();
    v8s a0 = *(const v8s*)&As[(wm      + fr)*40 + fk*8];
    v8s a1 = *(const v8s*)&As[(wm + 16 + fr)*40 + fk*8];
    v8s b0 = *(const v8s*)&Bs[(wn      + fr)*40 + fk*8];
    v8s b1 = *(const v8s*)&Bs[(wn + 16 + fr)*40 + fk*8];
    acc[0][0] = __builtin_amdgcn_mfma_f32_16x16x32_bf16(a0,b0,acc[0][0],0,0,0);
    acc[0][1] = __builtin_amdgcn_mfma_f32_16x16x32_bf16(a0,b1,acc[0][1],0,0,0);
    acc[1][0] = __builtin_amdgcn_mfma_f32_16x16x32_bf16(a1,b0,acc[1][0],0,0,0);
    acc[1][1] = __builtin_amdgcn_mfma_f32_16x16x32_bf16(a1,b1,acc[1][1],0,0,0);
  }
#pragma unroll
  for (int nj = 0; nj < 2; nj++) {
    int col = n_base + wn + nj*16 + fr;
    float bpv = bpre[col];
#pragma unroll
    for (int mi = 0; mi < 2; mi++) {
#pragma unroll
      for (int r = 0; r < 4; r++) {
        int row = m_base + wm + mi*16 + fk*4 + r;
        if (row < N) y[(size_t)row*256 + col] = acc[mi][nj][r] + bpv;
      }
    }
  }
}

// =====================================================================
// K2: block = (group g, 256-node chunk). Weight reads wave-uniform.
// =====================================================================
__global__ __launch_bounds__(256) void k_gnqkv(
    const float* __restrict__ y, const float* __restrict__ wq,
    const float* __restrict__ wk, const float* __restrict__ wv,
    u16* __restrict__ qo, u16* __restrict__ ko, u16* __restrict__ vo, int N)
{
  __shared__ __align__(16) float wL[3*512];
  const int t = threadIdx.x;
  const int g = blockIdx.x & 15;
  const int c = blockIdx.x >> 4;
  {
    const float* srcs[3] = {wq, wk, wv};
#pragma unroll
    for (int tz = 0; tz < 3; tz++) {
      wL[tz*512 + t]       = srcs[tz][g*512 + t];
      wL[tz*512 + t + 256] = srcs[tz][g*512 + t + 256];
    }
  }
  __syncthreads();
  const int node = c*256 + t;
  if (node >= N) return;

  const float* yp = y + (size_t)node*256 + g*16;
  float4 v0 = *(const float4*)yp;
  float4 v1 = *(const float4*)(yp + 4);
  float4 v2 = *(const float4*)(yp + 8);
  float4 v3 = *(const float4*)(yp + 12);
  float a[16] = {v0.x,v0.y,v0.z,v0.w, v1.x,v1.y,v1.z,v1.w,
                 v2.x,v2.y,v2.z,v2.w, v3.x,v3.y,v3.z,v3.w};
  float mu = 0.f;
#pragma unroll
  for (int i = 0; i < 16; i++) mu += a[i];
  mu *= 0.0625f;
  float s2 = 0.f;
#pragma unroll
  for (int i = 0; i < 16; i++) { float d = a[i]-mu; s2 = fmaf(d,d,s2); }
  float inv = rsqrtf(s2*0.0625f + GN_EPS);
  float yn[16];
#pragma unroll
  for (int i = 0; i < 16; i++) yn[i] = (a[i]-mu)*inv;

  u16* outs[3] = {qo, ko, vo};
#pragma unroll
  for (int tz = 0; tz < 3; tz++) {
#pragma unroll
    for (int s = 0; s < 2; s++) {
      u32 p[8];
#pragma unroll
      for (int o = 0; o < 16; o++) {
        const float* row = &wL[tz*512 + (s*16 + o)*16];
        float4 W0 = *(const float4*)row;
        float4 W1 = *(const float4*)(row + 4);
        float4 W2 = *(const float4*)(row + 8);
        float4 W3 = *(const float4*)(row + 12);
        float w[16] = {W0.x,W0.y,W0.z,W0.w,W1.x,W1.y,W1.z,W1.w,
                       W2.x,W2.y,W2.z,W2.w,W3.x,W3.y,W3.z,W3.w};
        float d = 0.f;
#pragma unroll
        for (int i = 0; i < 16; i++) d = fmaf(yn[i], w[i], d);
        if (tz < 2) d = __expf(d*0.25f);
        if (o & 1) p[o>>1] |= (u32)f2bf(d) << 16;
        else       p[o>>1]  = (u32)f2bf(d);
      }
      u16* dst = outs[tz] + (size_t)node*512 + g*32 + s*16;
      *(uint4*)dst       = make_uint4(p[0],p[1],p[2],p[3]);
      *(uint4*)(dst + 8) = make_uint4(p[4],p[5],p[6],p[7]);
    }
  }
}

// =====================================================================
// K3 (512 threads): per-graph fused segment-sum + att.
// Phase 1: two node-halves (waves 0-3 / 4-7) accumulate kv/ks in
//   registers over alternating nodes, direct-from-global, unrolled x2.
// Reduce: half0 -> LDS (padded stride 20), half1 adds its own.
// Phase 2 (half1 only): out1 = kv + xres; kv -> LDS bf16 stride 280.
// Phase 3 (all 512): per (node, head) att, 16 node-slots/iter.
// =====================================================================
__global__ __launch_bounds__(512) void k_segatt(
    const u16* __restrict__ xk, const u16* __restrict__ xv,
    const u16* __restrict__ xq, const float* __restrict__ xres,
    const int* __restrict__ bounds,
    float* __restrict__ out1, u16* __restrict__ att, int N)
{
  __shared__ __align__(16) float red[512*20];   // 40 KB (32nh x 16h rows, pad 20)
  __shared__ __align__(16) float kspart[512];   // 2 KB
  __shared__ __align__(16) u16 kvs[32*280];     // 17.5 KB
  __shared__ float kss[32*17];                  // 2.2 KB
  const int b = blockIdx.x, t = threadIdx.x;
  const int lo = bounds[b], hi = bounds[b+1];
  const int half = t >> 8;                 // 0: waves 0-3, 1: waves 4-7
  const int nh = (t >> 3) & 31, hp = t & 7;

  float kv[2][16];
#pragma unroll
  for (int r = 0; r < 2; r++)
#pragma unroll
    for (int v = 0; v < 16; v++) kv[r][v] = 0.f;
  float ks0 = 0.f, ks1 = 0.f;

  // ---- phase 1: direct-from-global, interleaved halves, unroll x2 ----
  const size_t koff = (size_t)nh*16 + 2*hp;
  const size_t voff = (size_t)nh*16;
  int node = lo + half;
  for (; node + 2 < hi; node += 4) {
    u32  kw0 = *(const u32*) (xk + (size_t)node*512 + koff);
    uint4 Va0 = *(const uint4*)(xv + (size_t)node*512 + voff);
    uint4 Va1 = *(const uint4*)(xv + (size_t)node*512 + voff + 8);
    u32  kw1 = *(const u32*) (xk + (size_t)(node+2)*512 + koff);
    uint4 Vb0 = *(const uint4*)(xv + (size_t)(node+2)*512 + voff);
    uint4 Vb1 = *(const uint4*)(xv + (size_t)(node+2)*512 + voff + 8);
    float a0 = bflo(kw0), a1 = bfhi(kw0);
    float b0 = bflo(kw1), b1 = bfhi(kw1);
    float va[16], vb[16];
    unpack8(Va0, va); unpack8(Va1, va + 8);
    unpack8(Vb0, vb); unpack8(Vb1, vb + 8);
    ks0 += a0 + b0; ks1 += a1 + b1;
#pragma unroll
    for (int v = 0; v < 16; v++) {
      kv[0][v] = fmaf(a0, va[v], kv[0][v]);
      kv[1][v] = fmaf(a1, va[v], kv[1][v]);
      kv[0][v] = fmaf(b0, vb[v], kv[0][v]);
      kv[1][v] = fmaf(b1, vb[v], kv[1][v]);
    }
  }
  if (node < hi) {
    u32  kw = *(const u32*) (xk + (size_t)node*512 + koff);
    uint4 V0 = *(const uint4*)(xv + (size_t)node*512 + voff);
    uint4 V1 = *(const uint4*)(xv + (size_t)node*512 + voff + 8);
    float k0 = bflo(kw), k1 = bfhi(kw);
    float vf[16]; unpack8(V0, vf); unpack8(V1, vf + 8);
    ks0 += k0; ks1 += k1;
#pragma unroll
    for (int v = 0; v < 16; v++) {
      kv[0][v] = fmaf(k0, vf[v], kv[0][v]);
      kv[1][v] = fmaf(k1, vf[v], kv[1][v]);
    }
  }

  // ---- reduce halves ----
  if (half == 0) {
#pragma unroll
    for (int r = 0; r < 2; r++) {
      float* rp = &red[(nh*16 + 2*hp + r)*20];
      *(float4*)rp       = make_float4(kv[r][0], kv[r][1], kv[r][2], kv[r][3]);
      *(float4*)(rp + 4) = make_float4(kv[r][4], kv[r][5], kv[r][6], kv[r][7]);
      *(float4*)(rp + 8) = make_float4(kv[r][8], kv[r][9], kv[r][10],kv[r][11]);
      *(float4*)(rp + 12)= make_float4(kv[r][12],kv[r][13],kv[r][14],kv[r][15]);
    }
    kspart[nh*16 + 2*hp]     = ks0;
    kspart[nh*16 + 2*hp + 1] = ks1;
  }
  __syncthreads();

  if (half == 1) {
#pragma unroll
    for (int r = 0; r < 2; r++) {
      const float* rp = &red[(nh*16 + 2*hp + r)*20];
      float4 R0 = *(const float4*)rp;
      float4 R1 = *(const float4*)(rp + 4);
      float4 R2 = *(const float4*)(rp + 8);
      float4 R3 = *(const float4*)(rp + 12);
      kv[r][0] += R0.x; kv[r][1] += R0.y; kv[r][2] += R0.z; kv[r][3] += R0.w;
      kv[r][4] += R1.x; kv[r][5] += R1.y; kv[r][6] += R1.z; kv[r][7] += R1.w;
      kv[r][8] += R2.x; kv[r][9] += R2.y; kv[r][10]+= R2.z; kv[r][11]+= R2.w;
      kv[r][12]+= R3.x; kv[r][13]+= R3.y; kv[r][14]+= R3.z; kv[r][15]+= R3.w;
    }
    ks0 += kspart[nh*16 + 2*hp];
    ks1 += kspart[nh*16 + 2*hp + 1];
    kss[nh*17 + 2*hp]     = ks0;
    kss[nh*17 + 2*hp + 1] = ks1;

    // ---- phase 2: out1 = kv + xres; kv -> LDS (bf16) ----
#pragma unroll
    for (int r = 0; r < 2; r++) {
      int h = 2*hp + r;
      size_t idx = ((size_t)(b*32 + nh)*16 + h)*16;
      const float* xp = xres + idx;
      float4 X0 = *(const float4*)xp;
      float4 X1 = *(const float4*)(xp + 4);
      float4 X2 = *(const float4*)(xp + 8);
      float4 X3 = *(const float4*)(xp + 12);
      float xf[16] = {X0.x,X0.y,X0.z,X0.w,X1.x,X1.y,X1.z,X1.w,
                      X2.x,X2.y,X2.z,X2.w,X3.x,X3.y,X3.z,X3.w};
      float o[16];
#pragma unroll
      for (int j = 0; j < 16; j++) o[j] = kv[r][j] + xf[j];
      float* op = out1 + idx;
      *(float4*)op        = make_float4(o[0],o[1],o[2],o[3]);
      *(float4*)(op + 4)  = make_float4(o[4],o[5],o[6],o[7]);
      *(float4*)(op + 8)  = make_float4(o[8],o[9],o[10],o[11]);
      *(float4*)(op + 12) = make_float4(o[12],o[13],o[14],o[15]);
      u16* lp = &kvs[nh*280 + h*16];
      *(uint4*)lp       = make_uint4(pack2(o[0],o[1]),  pack2(o[2],o[3]),
                                     pack2(o[4],o[5]),  pack2(o[6],o[7]));
      *(uint4*)(lp + 8) = make_uint4(pack2(o[8],o[9]),  pack2(o[10],o[11]),
                                     pack2(o[12],o[13]),pack2(o[14],o[15]));
    }
  }
  __syncthreads();

  // ---- phase 3: att, 16 node-slots per iter ----
  const int nh2 = t & 31, ns = t >> 5;   // ns 0..15
  for (int n0 = lo; n0 < hi; n0 += 16) {
    int nodei = n0 + ns;
    if (nodei >= hi) continue;
    const u16* qp = xq + (size_t)nodei*512 + nh2*16;
    uint4 Q0 = *(const uint4*)qp;
    uint4 Q1 = *(const uint4*)(qp + 8);
    float q[16]; unpack8(Q0, q); unpack8(Q1, q + 8);
    const float* ksp = &kss[nh2*17];
    float denom = 0.f;
#pragma unroll
    for (int i = 0; i < 16; i++) denom = fmaf(q[i], ksp[i], denom);
    float inv = 1.0f / fmaxf(denom, 1e-20f);
    float a[16];
#pragma unroll
    for (int v = 0; v < 16; v++) a[v] = 0.f;
    const u16* kvp = &kvs[nh2*280];
#pragma unroll
    for (int h = 0; h < 16; h++) {
      float qh = q[h] * inv;
      uint4 W0 = *(const uint4*)(kvp + h*16);
      uint4 W1 = *(const uint4*)(kvp + h*16 + 8);
      float w[16]; unpack8(W0, w); unpack8(W1, w + 8);
#pragma unroll
      for (int v = 0; v < 16; v++) a[v] = fmaf(qh, w[v], a[v]);
    }
    u32 p[8];
#pragma unroll
    for (int j = 0; j < 8; j++) p[j] = pack2(a[2*j], a[2*j+1]);
    u16* dst = att + (size_t)nodei*512 + nh2*16;
    *(uint4*)dst       = make_uint4(p[0],p[1],p[2],p[3]);
    *(uint4*)(dst + 8) = make_uint4(p[4],p[5],p[6],p[7]);
  }
}

// =====================================================================
// K5 (MFMA): out0 = exp(log_scale) * (att @ w_post^T + b_post), K=512.
// =====================================================================
__global__ __launch_bounds__(256) void k_post(
    const u16* __restrict__ att, const float* __restrict__ wpost,
    const float* __restrict__ bpost, const float* __restrict__ ls,
    float* __restrict__ out0, int N, int nbm)
{
  __shared__ __align__(16) u16 As[64*40];
  __shared__ __align__(16) u16 Bs[64*40];
  const int t = threadIdx.x;
  const int bm = blockIdx.x % nbm;
  const int bn = blockIdx.x / nbm;          // 0..3
  const int m_base = bm*64, n_base = bn*64;
  const int w = t >> 6, lane = t & 63;
  const int wm = (w >> 1)*32, wn = (w & 1)*32;
  const int fr = lane & 15, fk = lane >> 4;
  const int srow = t >> 2, scol = (t & 3)*8;

  v4f acc[2][2];
#pragma unroll
  for (int i = 0; i < 2; i++)
#pragma unroll
    for (int j = 0; j < 2; j++) acc[i][j] = (v4f){0.f,0.f,0.f,0.f};

  for (int k0 = 0; k0 < 512; k0 += 32) {
    __syncthreads();
    {
      int gm = m_base + srow;
      uint4 av = make_uint4(0u,0u,0u,0u);
      if (gm < N) av = *(const uint4*)(att + (size_t)gm*512 + k0 + scol);
      *(uint4*)&As[srow*40 + scol] = av;
      uint4 bv = loadpack8(wpost + (size_t)(n_base + srow)*512 + k0 + scol);
      *(uint4*)&Bs[srow*40 + scol] = bv;
    }
    __syncthreads();
    v8s a0 = *(const v8s*)&As[(wm      + fr)*40 + fk*8];
    v8s a1 = *(const v8s*)&As[(wm + 16 + fr)*40 + fk*8];
    v8s b0 = *(const v8s*)&Bs[(wn      + fr)*40 + fk*8];
    v8s b1 = *(const v8s*)&Bs[(wn + 16 + fr)*40 + fk*8];
    acc[0][0] = __builtin_amdgcn_mfma_f32_16x16x32_bf16(a0,b0,acc[0][0],0,0,0);
    acc[0][1] = __builtin_amdgcn_mfma_f32_16x16x32_bf16(a0,b1,acc[0][1],0,0,0);
    acc[1][0] = __builtin_amdgcn_mfma_f32_16x16x32_bf16(a1,b0,acc[1][0],0,0,0);
    acc[1][1] = __builtin_amdgcn_mfma_f32_16x16x32_bf16(a1,b1,acc[1][1],0,0,0);
  }
#pragma unroll
  for (int nj = 0; nj < 2; nj++) {
    int col = n_base + wn + nj*16 + fr;
    float bpv = bpost[col];
    float e   = __expf(ls[col]);
#pragma unroll
    for (int mi = 0; mi < 2; mi++) {
#pragma unroll
      for (int r = 0; r < 4; r++) {
        int row = m_base + wm + mi*16 + fk*4 + r;
        if (row < N) out0[(size_t)row*256 + col] = e*(acc[mi][nj][r] + bpv);
      }
    }
  }
}

// =====================================================================
extern "C" void kernel_launch(void* const* d_in, const int* in_sizes, int n_in,
                              void* d_out, int out_size, void* d_ws, size_t ws_size,
                              hipStream_t stream)
{
  const float* x     = (const float*)d_in[0];
  const float* xres  = (const float*)d_in[1];
  const int*   batch = (const int*)d_in[2];
  const float* wpre  = (const float*)d_in[4];
  const float* bpre  = (const float*)d_in[5];
  const float* wq    = (const float*)d_in[6];
  const float* wk    = (const float*)d_in[7];
  const float* wv    = (const float*)d_in[8];
  const float* wpost = (const float*)d_in[9];
  const float* bpost = (const float*)d_in[10];
  const float* ls    = (const float*)d_in[11];

  const int N = in_sizes[0] / 256;     // 20000 nodes
  const int B = in_sizes[1] / 8192;    // 1024 graphs
  const int nbm = (N + 63) / 64;       // 313 row tiles
  const int nchunk = (N + 255) / 256;  // 79 node chunks

  char* ws = (char*)d_ws;
  size_t off = 0;
  int*   flags  = (int*)(ws + off); off += 256;
  int*   bounds = (int*)(ws + off); off += ((size_t)B + 64) * 4;
  float* y      = (float*)(ws + off);                          // reused for att
  u16*   att    = (u16*)(ws + off);  off += (size_t)N * 1024;
  u16*   q      = (u16*)(ws + off);  off += (size_t)N * 1024;
  u16*   kten   = (u16*)(ws + off);  off += (size_t)N * 1024;
  u16*   vten   = (u16*)(ws + off);  off += (size_t)N * 1024;

  float* out0 = (float*)d_out;
  float* out1 = out0 + (size_t)N * 256;

  hipMemsetAsync(flags, 0, 4, stream);
  k_detect<<<nchunk,         256, 0, stream>>>(batch, N, flags);
  k_bounds<<<nchunk,         256, 0, stream>>>(batch, flags, N, B, bounds);
  k_pre   <<<nbm * 4,        256, 0, stream>>>(x, wpre, bpre, y, N, nbm);
  k_gnqkv <<<nchunk * 16,    256, 0, stream>>>(y, wq, wk, wv, q, kten, vten, N);
  k_segatt<<<B,              512, 0, stream>>>(kten, vten, q, xres, bounds,
                                               out1, att, N);
  k_post  <<<nbm * 4,        256, 0, stream>>>(att, wpost, bpost, ls, out0, N, nbm);
}